// Round 1
// baseline (3283.101 us; speedup 1.0000x reference)
//
#include <hip/hip_runtime.h>
#include <cstdint>

// Direct 3x3 conv, padding 1, stride STRIDE. One block computes a 16x16 tile
// of output pixels for COUT output channels (blockIdx.z selects a channel
// group of COUT channels). Input tile (+halo) staged in LDS per input channel;
// each thread keeps COUT accumulators in registers. Weight reads are uniform
// across the wave -> scalar path / L1-cached.
// ACT: 0 = none, 1 = relu, 2 = tanh
template<int COUT, int STRIDE, int ACT>
__global__ __launch_bounds__(256)
void conv3x3_k(const float* __restrict__ in, int Cin, int Hin, int Win,
               const float* __restrict__ w, const float* __restrict__ bias,
               float* __restrict__ out, int Hout, int Wout)
{
    constexpr int T = 16;
    constexpr int SPAN = (T - 1) * STRIDE + 3;   // 18 (s=1) or 33 (s=2)
    __shared__ float tile[SPAN * SPAN];

    const int tx = threadIdx.x & 15;
    const int ty = threadIdx.x >> 4;
    const int ox = blockIdx.x * T + tx;
    const int oy = blockIdx.y * T + ty;
    const int ix0 = blockIdx.x * T * STRIDE - 1;
    const int iy0 = blockIdx.y * T * STRIDE - 1;
    const int gz = blockIdx.z;

    const float* wg   = w    + (size_t)gz * COUT * Cin * 9;
    const float* bg   = bias + (size_t)gz * COUT;
    float*       outg = out  + (size_t)gz * COUT * Hout * Wout;

    float acc[COUT];
    #pragma unroll
    for (int o = 0; o < COUT; ++o) acc[o] = bg[o];

    for (int c = 0; c < Cin; ++c) {
        const float* inc = in + (size_t)c * Hin * Win;
        __syncthreads();   // protect previous iteration's tile reads
        for (int idx = threadIdx.x; idx < SPAN * SPAN; idx += 256) {
            int yy = idx / SPAN, xx = idx - yy * SPAN;
            int gy = iy0 + yy, gx = ix0 + xx;
            float v = 0.f;
            if ((unsigned)gy < (unsigned)Hin && (unsigned)gx < (unsigned)Win)
                v = inc[(size_t)gy * Win + gx];
            tile[idx] = v;
        }
        __syncthreads();

        float p[9];
        #pragma unroll
        for (int dy = 0; dy < 3; ++dy)
            #pragma unroll
            for (int dx = 0; dx < 3; ++dx)
                p[dy * 3 + dx] = tile[(ty * STRIDE + dy) * SPAN + tx * STRIDE + dx];

        const float* wc = wg + c * 9;
        #pragma unroll
        for (int o = 0; o < COUT; ++o) {
            const float* wo = wc + (size_t)o * Cin * 9;
            float a = acc[o];
            #pragma unroll
            for (int k = 0; k < 9; ++k) a = fmaf(p[k], wo[k], a);
            acc[o] = a;
        }
    }

    if (ox < Wout && oy < Hout) {
        const size_t pix = (size_t)oy * Wout + ox;
        #pragma unroll
        for (int o = 0; o < COUT; ++o) {
            float v = acc[o];
            if (ACT == 1) v = fmaxf(v, 0.f);
            else if (ACT == 2) v = tanhf(v);
            outg[(size_t)o * Hout * Wout + pix] = v;
        }
    }
}

__global__ __launch_bounds__(256)
void maxpool2_k(const float* __restrict__ in, int C, int Hin, int Win,
                float* __restrict__ out)
{
    int Ho = Hin >> 1, Wo = Win >> 1;
    int n = C * Ho * Wo;
    for (int i = blockIdx.x * blockDim.x + threadIdx.x; i < n;
         i += gridDim.x * blockDim.x) {
        int x = i % Wo; int t = i / Wo; int y = t % Ho; int c = t / Ho;
        const float* p = in + ((size_t)c * Hin + 2 * y) * Win + 2 * x;
        out[i] = fmaxf(fmaxf(p[0], p[1]), fmaxf(p[Win], p[Win + 1]));
    }
}

// h: (64,8,8) -> g[c]=mean -> Wp[j] = lin_b[j] + sum_c g[c]*lin_w[j*64+c]
__global__ void meanlin_k(const float* __restrict__ h,
                          const float* __restrict__ lw,
                          const float* __restrict__ lb,
                          float* __restrict__ wm)
{
    __shared__ float g[64];
    int t = threadIdx.x;
    if (t < 64) {
        float s = 0.f;
        for (int p = 0; p < 64; ++p) s += h[t * 64 + p];
        g[t] = s * (1.f / 64.f);
    }
    __syncthreads();
    if (t < 30) {
        float s = lb[t];
        for (int c = 0; c < 64; ++c) s = fmaf(g[c], lw[t * 64 + c], s);
        wm[t] = s;
    }
}

// out[o,h,w] = sum_k Wm[o,k] * feats[k], feats from I3 = last 3 channels of I
__global__ __launch_bounds__(256)
void final_k(const float* __restrict__ I3, const float* __restrict__ wm,
             float* __restrict__ out)
{
    __shared__ float W[30];
    if (threadIdx.x < 30) W[threadIdx.x] = wm[threadIdx.x];
    __syncthreads();
    const int HW = 512 * 512;
    for (int i = blockIdx.x * blockDim.x + threadIdx.x; i < HW;
         i += gridDim.x * blockDim.x) {
        float r = I3[i], g = I3[HW + i], b = I3[2 * HW + i];
        float f[10] = { r * r, r * g, r * b, r, g * g, g * b, g, b * b, b, 1.f };
        #pragma unroll
        for (int o = 0; o < 3; ++o) {
            float s = 0.f;
            #pragma unroll
            for (int k = 0; k < 10; ++k) s = fmaf(W[o * 10 + k], f[k], s);
            out[(size_t)o * HW + i] = s;
        }
    }
}

extern "C" void kernel_launch(void* const* d_in, const int* in_sizes, int n_in,
                              void* d_out, int out_size, void* d_ws, size_t ws_size,
                              hipStream_t stream)
{
    const float* x      = (const float*)d_in[0];
    const float* low0_w = (const float*)d_in[1];
    const float* low0_b = (const float*)d_in[2];
    const float* rh_w   = (const float*)d_in[3];   // (4,61,61,3,3)
    const float* rh_b   = (const float*)d_in[4];   // (4,61)
    const float* lh_w   = (const float*)d_in[5];   // (4,3,3,3,3)
    const float* lh_b   = (const float*)d_in[6];   // (4,3)
    const float* hl0_w  = (const float*)d_in[7];   // (64,61,3,3)
    const float* hl0_b  = (const float*)d_in[8];   // (64,)
    const float* hl_w   = (const float*)d_in[9];   // (3,64,64,3,3)
    const float* hl_b   = (const float*)d_in[10];  // (3,64)
    const float* lin_w  = (const float*)d_in[11];  // (30,64)
    const float* lin_b  = (const float*)d_in[12];  // (30,)
    float* out = (float*)d_out;

    const size_t HW = 512 * 512;
    float* A  = (float*)d_ws;                      // 64*HW
    float* B  = A + 64 * HW;                       // 64*HW
    float* C  = B + 64 * HW;                       // 64*256*256
    float* D  = C + (size_t)64 * 256 * 256;        // 64*128*128
    float* WM = D + (size_t)64 * 128 * 128;        // 30

    dim3 blk(256);
    dim3 g512(32, 32, 1);

    // I = conv(x)
    conv3x3_k<64, 1, 0><<<g512, blk, 0, stream>>>(x, 3, 512, 512,
                                                  low0_w, low0_b, A, 512, 512);

    float* cur = A; float* nxt = B;
    for (int i = 0; i < 4; ++i) {
        conv3x3_k<61, 1, 1><<<g512, blk, 0, stream>>>(
            cur, 61, 512, 512, rh_w + (size_t)i * 61 * 61 * 9, rh_b + i * 61,
            nxt, 512, 512);
        conv3x3_k<3, 1, 2><<<g512, blk, 0, stream>>>(
            cur + 61 * HW, 3, 512, 512, lh_w + (size_t)i * 81, lh_b + i * 3,
            nxt + 61 * HW, 512, 512);
        float* t = cur; cur = nxt; nxt = t;
    }
    // final I is in `cur` (== A after 4 swaps)

    // h = conv(I[:, :61]) -> 64ch
    conv3x3_k<64, 1, 0><<<g512, blk, 0, stream>>>(cur, 61, 512, 512,
                                                  hl0_w, hl0_b, nxt, 512, 512);

    // stage 0: 512 -> conv(s2) 256 -> pool 128
    conv3x3_k<16, 2, 1><<<dim3(16, 16, 4), blk, 0, stream>>>(
        nxt, 64, 512, 512, hl_w, hl_b, C, 256, 256);
    maxpool2_k<<<dim3(1024), blk, 0, stream>>>(C, 64, 256, 256, D);

    // stage 1: 128 -> 64 -> 32
    conv3x3_k<16, 2, 1><<<dim3(4, 4, 4), blk, 0, stream>>>(
        D, 64, 128, 128, hl_w + (size_t)1 * 64 * 64 * 9, hl_b + 64, C, 64, 64);
    maxpool2_k<<<dim3(256), blk, 0, stream>>>(C, 64, 64, 64, D);

    // stage 2: 32 -> 16 -> 8
    conv3x3_k<16, 2, 1><<<dim3(1, 1, 4), blk, 0, stream>>>(
        D, 64, 32, 32, hl_w + (size_t)2 * 64 * 64 * 9, hl_b + 128, C, 16, 16);
    maxpool2_k<<<dim3(64), blk, 0, stream>>>(C, 64, 16, 16, D);

    // g = mean(h); Wp = g @ lin_w.T + lin_b
    meanlin_k<<<dim3(1), dim3(64), 0, stream>>>(D, lin_w, lin_b, WM);

    // out = einsum('ok,bkhw->bohw', Wm, feats(I[:,61:]))
    final_k<<<dim3(2048), blk, 0, stream>>>(cur + 61 * HW, WM, out);
}

// Round 2
// 1270.615 us; speedup vs baseline: 2.5839x; 2.5839x over previous
//
#include <hip/hip_runtime.h>
#include <cstdint>

typedef _Float16 half8 __attribute__((ext_vector_type(8)));
typedef float f32x4 __attribute__((ext_vector_type(4)));

#define HW_ (512*512)

// ---------------- fp32 VALU direct conv (kept for low0 / lh / stride-2) ----
template<int COUT, int STRIDE, int ACT>
__global__ __launch_bounds__(256)
void conv3x3_k(const float* __restrict__ in, int Cin, int Hin, int Win,
               const float* __restrict__ w, const float* __restrict__ bias,
               float* __restrict__ out, int Hout, int Wout)
{
    constexpr int T = 16;
    constexpr int SPAN = (T - 1) * STRIDE + 3;
    __shared__ float tile[SPAN * SPAN];

    const int tx = threadIdx.x & 15;
    const int ty = threadIdx.x >> 4;
    const int ox = blockIdx.x * T + tx;
    const int oy = blockIdx.y * T + ty;
    const int ix0 = blockIdx.x * T * STRIDE - 1;
    const int iy0 = blockIdx.y * T * STRIDE - 1;
    const int gz = blockIdx.z;

    const float* wg   = w    + (size_t)gz * COUT * Cin * 9;
    const float* bg   = bias + (size_t)gz * COUT;
    float*       outg = out  + (size_t)gz * COUT * Hout * Wout;

    float acc[COUT];
    #pragma unroll
    for (int o = 0; o < COUT; ++o) acc[o] = bg[o];

    for (int c = 0; c < Cin; ++c) {
        const float* inc = in + (size_t)c * Hin * Win;
        __syncthreads();
        for (int idx = threadIdx.x; idx < SPAN * SPAN; idx += 256) {
            int yy = idx / SPAN, xx = idx - yy * SPAN;
            int gy = iy0 + yy, gx = ix0 + xx;
            float v = 0.f;
            if ((unsigned)gy < (unsigned)Hin && (unsigned)gx < (unsigned)Win)
                v = inc[(size_t)gy * Win + gx];
            tile[idx] = v;
        }
        __syncthreads();

        float p[9];
        #pragma unroll
        for (int dy = 0; dy < 3; ++dy)
            #pragma unroll
            for (int dx = 0; dx < 3; ++dx)
                p[dy * 3 + dx] = tile[(ty * STRIDE + dy) * SPAN + tx * STRIDE + dx];

        const float* wc = wg + c * 9;
        #pragma unroll
        for (int o = 0; o < COUT; ++o) {
            const float* wo = wc + (size_t)o * Cin * 9;
            float a = acc[o];
            #pragma unroll
            for (int k = 0; k < 9; ++k) a = fmaf(p[k], wo[k], a);
            acc[o] = a;
        }
    }

    if (ox < Wout && oy < Hout) {
        const size_t pix = (size_t)oy * Wout + ox;
        #pragma unroll
        for (int o = 0; o < COUT; ++o) {
            float v = acc[o];
            if (ACT == 1) v = fmaxf(v, 0.f);
            else if (ACT == 2) v = tanhf(v);
            outg[(size_t)o * Hout * Wout + pix] = v;
        }
    }
}

// ---------------- weight transform: fp32 (O,61,3,3) -> frag-linear fp16 ----
// Layout per layer (36864 halfs): chunk ci = s*8 + kk*4 + m (s=tap 0..8,
// kk=c-chunk 0..1, m=M-frag 0..3), 512 halfs per chunk = lane*8 + j.
// Element (lane,j): A[o = m*16 + (lane&15)][c = kk*32 + (lane>>4)*8 + j],
// zero-padded for o>=O or c>=61.  Matches mfma_f32_16x16x32_f16 A-frag.
__global__ __launch_bounds__(256) void wtrans_k(
    const float* __restrict__ rh_w, const float* __restrict__ hl0_w,
    _Float16* __restrict__ wt)
{
    int t = blockIdx.x * 256 + threadIdx.x;
    if (t >= 5 * 4608) return;
    int layer = t / 4608;
    int r = t - layer * 4608;
    int lane = r & 63, ci = r >> 6;
    int m = ci & 3, kk = (ci >> 2) & 1, s = ci >> 3;
    int o = m * 16 + (lane & 15);
    int cb = kk * 32 + ((lane >> 4) & 3) * 8;
    const float* w; int O;
    if (layer < 4) { w = rh_w + (size_t)layer * 61 * 61 * 9; O = 61; }
    else           { w = hl0_w;                              O = 64; }
    half8 v;
    #pragma unroll
    for (int j = 0; j < 8; ++j) {
        int c = cb + j;
        float f = (o < O && c < 61) ? w[((size_t)o * 61 + c) * 9 + s] : 0.f;
        v[j] = (_Float16)f;
    }
    *(half8*)(wt + (size_t)layer * 36864 + (size_t)r * 8) = v;
}

// ---------------- MFMA implicit-GEMM conv, K=61x9, 512x512, pad 1 ---------
// Block: 16x16 pixel tile, 4 waves; wave w owns tile rows 4w..4w+3.
// in_t LDS: fp16 [ipix(0..323)][c(0..63)], XOR swizzle (c ^ ((ipix&7)<<3)).
// A-frags read from pre-transformed global wt (coalesced, L2-resident),
// ping-pong prefetched one tap ahead. No barriers in the main loop.
template<int O, int ACT>
__global__ __launch_bounds__(256, 2)
void conv_mfma_k(const float* __restrict__ in, const _Float16* __restrict__ wt,
                 const float* __restrict__ bias, float* __restrict__ out)
{
    __shared__ _Float16 __attribute__((aligned(16))) in_t[324 * 64];
    const int tid = threadIdx.x;
    const int l = tid & 63, wv = tid >> 6;
    const int px = l & 15, g = l >> 4;
    const int bx = blockIdx.x, by = blockIdx.y;
    const int iy0 = by * 16 - 1, ix0 = bx * 16 - 1;

    // stage input tile (all 64 channels; channels>=61 get zero weights)
    for (int c = 0; c < 64; ++c) {
        const float* inc = in + (size_t)c * HW_;
        for (int p = tid; p < 324; p += 256) {
            int iy = p / 18, ix = p - iy * 18;
            int gy = iy0 + iy, gx = ix0 + ix;
            float v = ((unsigned)gy < 512u && (unsigned)gx < 512u)
                          ? inc[gy * 512 + gx] : 0.f;
            in_t[p * 64 + (c ^ ((p & 7) << 3))] = (_Float16)v;
        }
    }
    __syncthreads();

    float bs[4][4];
    #pragma unroll
    for (int m = 0; m < 4; ++m)
        #pragma unroll
        for (int r = 0; r < 4; ++r) {
            int o = m * 16 + g * 4 + r;
            bs[m][r] = (o < O) ? bias[o] : 0.f;
        }

    f32x4 acc[4][4];
    #pragma unroll
    for (int m = 0; m < 4; ++m)
        #pragma unroll
        for (int f = 0; f < 4; ++f) acc[m][f] = (f32x4){0.f, 0.f, 0.f, 0.f};

    const _Float16* wb = wt + (size_t)l * 8;
    half8 aA[8], aB[8];
    #pragma unroll
    for (int q = 0; q < 8; ++q) aA[q] = *(const half8*)(wb + q * 512);

    #pragma unroll
    for (int s = 0; s < 9; ++s) {
        asm volatile("" ::: "memory");   // fence: keep prefetch one tap ahead
        const half8* ac = (s & 1) ? aB : aA;
        half8*       an = (s & 1) ? aA : aB;
        if (s < 8) {
            #pragma unroll
            for (int q = 0; q < 8; ++q)
                an[q] = *(const half8*)(wb + ((s + 1) * 8 + q) * 512);
        }
        const int dy = s / 3, dx = s - dy * 3;
        #pragma unroll
        for (int f = 0; f < 4; ++f) {
            int ipix = (4 * wv + f + dy) * 18 + px + dx;
            int rb = ipix * 64, sw = (ipix & 7) << 3;
            #pragma unroll
            for (int kk = 0; kk < 2; ++kk) {
                half8 b = *(const half8*)&in_t[rb + ((kk * 32 + g * 8) ^ sw)];
                #pragma unroll
                for (int m = 0; m < 4; ++m)
                    acc[m][f] = __builtin_amdgcn_mfma_f32_16x16x32_f16(
                        ac[kk * 4 + m], b, acc[m][f], 0, 0, 0);
            }
        }
    }

    // epilogue: C/D layout col=lane&15 (pixel), row=(lane>>4)*4+r (channel)
    const int gx0 = bx * 16 + px;
    #pragma unroll
    for (int f = 0; f < 4; ++f) {
        const int gy = by * 16 + 4 * wv + f;
        float* orow = out + (size_t)gy * 512 + gx0;
        #pragma unroll
        for (int m = 0; m < 4; ++m)
            #pragma unroll
            for (int r = 0; r < 4; ++r) {
                int o = m * 16 + g * 4 + r;
                if (o < O) {
                    float v = acc[m][f][r] + bs[m][r];
                    if (ACT) v = fmaxf(v, 0.f);
                    orow[(size_t)o * HW_] = v;
                }
            }
    }
}

// ---------------- small tail kernels (unchanged) ---------------------------
__global__ __launch_bounds__(256)
void maxpool2_k(const float* __restrict__ in, int C, int Hin, int Win,
                float* __restrict__ out)
{
    int Ho = Hin >> 1, Wo = Win >> 1;
    int n = C * Ho * Wo;
    for (int i = blockIdx.x * blockDim.x + threadIdx.x; i < n;
         i += gridDim.x * blockDim.x) {
        int x = i % Wo; int t = i / Wo; int y = t % Ho; int c = t / Ho;
        const float* p = in + ((size_t)c * Hin + 2 * y) * Win + 2 * x;
        out[i] = fmaxf(fmaxf(p[0], p[1]), fmaxf(p[Win], p[Win + 1]));
    }
}

__global__ void meanlin_k(const float* __restrict__ h,
                          const float* __restrict__ lw,
                          const float* __restrict__ lb,
                          float* __restrict__ wm)
{
    __shared__ float g[64];
    int t = threadIdx.x;
    if (t < 64) {
        float s = 0.f;
        for (int p = 0; p < 64; ++p) s += h[t * 64 + p];
        g[t] = s * (1.f / 64.f);
    }
    __syncthreads();
    if (t < 30) {
        float s = lb[t];
        for (int c = 0; c < 64; ++c) s = fmaf(g[c], lw[t * 64 + c], s);
        wm[t] = s;
    }
}

__global__ __launch_bounds__(256)
void final_k(const float* __restrict__ I3, const float* __restrict__ wm,
             float* __restrict__ out)
{
    __shared__ float W[30];
    if (threadIdx.x < 30) W[threadIdx.x] = wm[threadIdx.x];
    __syncthreads();
    const int HW = 512 * 512;
    for (int i = blockIdx.x * blockDim.x + threadIdx.x; i < HW;
         i += gridDim.x * blockDim.x) {
        float r = I3[i], g = I3[HW + i], b = I3[2 * HW + i];
        float f[10] = { r * r, r * g, r * b, r, g * g, g * b, g, b * b, b, 1.f };
        #pragma unroll
        for (int o = 0; o < 3; ++o) {
            float s = 0.f;
            #pragma unroll
            for (int k = 0; k < 10; ++k) s = fmaf(W[o * 10 + k], f[k], s);
            out[(size_t)o * HW + i] = s;
        }
    }
}

extern "C" void kernel_launch(void* const* d_in, const int* in_sizes, int n_in,
                              void* d_out, int out_size, void* d_ws, size_t ws_size,
                              hipStream_t stream)
{
    const float* x      = (const float*)d_in[0];
    const float* low0_w = (const float*)d_in[1];
    const float* low0_b = (const float*)d_in[2];
    const float* rh_w   = (const float*)d_in[3];   // (4,61,61,3,3)
    const float* rh_b   = (const float*)d_in[4];   // (4,61)
    const float* lh_w   = (const float*)d_in[5];   // (4,3,3,3,3)
    const float* lh_b   = (const float*)d_in[6];   // (4,3)
    const float* hl0_w  = (const float*)d_in[7];   // (64,61,3,3)
    const float* hl0_b  = (const float*)d_in[8];   // (64,)
    const float* hl_w   = (const float*)d_in[9];   // (3,64,64,3,3)
    const float* hl_b   = (const float*)d_in[10];  // (3,64)
    const float* lin_w  = (const float*)d_in[11];  // (30,64)
    const float* lin_b  = (const float*)d_in[12];  // (30,)
    float* out = (float*)d_out;

    const size_t HW = 512 * 512;
    float* A  = (float*)d_ws;                      // 64*HW
    float* B  = A + 64 * HW;                       // 64*HW
    float* C  = B + 64 * HW;                       // 64*256*256
    float* D  = C + (size_t)64 * 256 * 256;        // 64*128*128
    float* WM = D + (size_t)64 * 128 * 128;        // 30
    // WT lives at the start of C: only used before stage0 ever writes C.
    _Float16* WT = (_Float16*)C;                   // 5*36864 halfs

    dim3 blk(256);
    dim3 g512(32, 32, 1);
    dim3 gmf(32, 32, 1);

    // pre-transform rh/hl0 weights to fragment-linear fp16
    wtrans_k<<<dim3((5 * 4608 + 255) / 256), blk, 0, stream>>>(rh_w, hl0_w, WT);

    // I = conv(x)  (fp32 VALU, Cin=3 — cheap and keeps I3 path exact)
    conv3x3_k<64, 1, 0><<<g512, blk, 0, stream>>>(x, 3, 512, 512,
                                                  low0_w, low0_b, A, 512, 512);

    float* cur = A; float* nxt = B;
    for (int i = 0; i < 4; ++i) {
        conv_mfma_k<61, 1><<<gmf, blk, 0, stream>>>(
            cur, WT + (size_t)i * 36864, rh_b + i * 61, nxt);
        conv3x3_k<3, 1, 2><<<g512, blk, 0, stream>>>(
            cur + 61 * HW, 3, 512, 512, lh_w + (size_t)i * 81, lh_b + i * 3,
            nxt + 61 * HW, 512, 512);
        float* t = cur; cur = nxt; nxt = t;
    }

    // h = conv(I[:, :61]) -> 64ch  (MFMA, no activation)
    conv_mfma_k<64, 0><<<gmf, blk, 0, stream>>>(
        cur, WT + (size_t)4 * 36864, hl0_b, nxt);

    // stage 0: 512 -> conv(s2) 256 -> pool 128
    conv3x3_k<16, 2, 1><<<dim3(16, 16, 4), blk, 0, stream>>>(
        nxt, 64, 512, 512, hl_w, hl_b, C, 256, 256);
    maxpool2_k<<<dim3(1024), blk, 0, stream>>>(C, 64, 256, 256, D);

    // stage 1: 128 -> 64 -> 32
    conv3x3_k<16, 2, 1><<<dim3(4, 4, 4), blk, 0, stream>>>(
        D, 64, 128, 128, hl_w + (size_t)1 * 64 * 64 * 9, hl_b + 64, C, 64, 64);
    maxpool2_k<<<dim3(256), blk, 0, stream>>>(C, 64, 64, 64, D);

    // stage 2: 32 -> 16 -> 8
    conv3x3_k<16, 2, 1><<<dim3(1, 1, 4), blk, 0, stream>>>(
        D, 64, 32, 32, hl_w + (size_t)2 * 64 * 64 * 9, hl_b + 128, C, 16, 16);
    maxpool2_k<<<dim3(64), blk, 0, stream>>>(C, 64, 16, 16, D);

    // g = mean(h); Wp = g @ lin_w.T + lin_b
    meanlin_k<<<dim3(1), dim3(64), 0, stream>>>(D, lin_w, lin_b, WM);

    // out = einsum('ok,bkhw->bohw', Wm, feats(I[:,61:]))
    final_k<<<dim3(2048), blk, 0, stream>>>(cur + 61 * HW, WM, out);
}

// Round 3
// 834.960 us; speedup vs baseline: 3.9320x; 1.5218x over previous
//
#include <hip/hip_runtime.h>
#include <cstdint>

typedef _Float16 half8 __attribute__((ext_vector_type(8)));
typedef float f32x4 __attribute__((ext_vector_type(4)));

#define HW_ (512*512)

// ---------------- fp32 VALU direct conv (kept for low0 / lh) --------------
template<int COUT, int STRIDE, int ACT>
__global__ __launch_bounds__(256)
void conv3x3_k(const float* __restrict__ in, int Cin, int Hin, int Win,
               const float* __restrict__ w, const float* __restrict__ bias,
               float* __restrict__ out, int Hout, int Wout)
{
    constexpr int T = 16;
    constexpr int SPAN = (T - 1) * STRIDE + 3;
    __shared__ float tile[SPAN * SPAN];

    const int tx = threadIdx.x & 15;
    const int ty = threadIdx.x >> 4;
    const int ox = blockIdx.x * T + tx;
    const int oy = blockIdx.y * T + ty;
    const int ix0 = blockIdx.x * T * STRIDE - 1;
    const int iy0 = blockIdx.y * T * STRIDE - 1;
    const int gz = blockIdx.z;

    const float* wg   = w    + (size_t)gz * COUT * Cin * 9;
    const float* bg   = bias + (size_t)gz * COUT;
    float*       outg = out  + (size_t)gz * COUT * Hout * Wout;

    float acc[COUT];
    #pragma unroll
    for (int o = 0; o < COUT; ++o) acc[o] = bg[o];

    for (int c = 0; c < Cin; ++c) {
        const float* inc = in + (size_t)c * Hin * Win;
        __syncthreads();
        for (int idx = threadIdx.x; idx < SPAN * SPAN; idx += 256) {
            int yy = idx / SPAN, xx = idx - yy * SPAN;
            int gy = iy0 + yy, gx = ix0 + xx;
            float v = 0.f;
            if ((unsigned)gy < (unsigned)Hin && (unsigned)gx < (unsigned)Win)
                v = inc[(size_t)gy * Win + gx];
            tile[idx] = v;
        }
        __syncthreads();

        float p[9];
        #pragma unroll
        for (int dy = 0; dy < 3; ++dy)
            #pragma unroll
            for (int dx = 0; dx < 3; ++dx)
                p[dy * 3 + dx] = tile[(ty * STRIDE + dy) * SPAN + tx * STRIDE + dx];

        const float* wc = wg + c * 9;
        #pragma unroll
        for (int o = 0; o < COUT; ++o) {
            const float* wo = wc + (size_t)o * Cin * 9;
            float a = acc[o];
            #pragma unroll
            for (int k = 0; k < 9; ++k) a = fmaf(p[k], wo[k], a);
            acc[o] = a;
        }
    }

    if (ox < Wout && oy < Hout) {
        const size_t pix = (size_t)oy * Wout + ox;
        #pragma unroll
        for (int o = 0; o < COUT; ++o) {
            float v = acc[o];
            if (ACT == 1) v = fmaxf(v, 0.f);
            else if (ACT == 2) v = tanhf(v);
            outg[(size_t)o * Hout * Wout + pix] = v;
        }
    }
}

// ---------------- weight transform: fp32 -> frag-linear fp16 --------------
// 8 layers: 0-3 rh (O=61,CIN=61), 4 hl0 (O=64,CIN=61), 5-7 hl (O=64,CIN=64).
// Per layer 36864 halfs: chunk ci = s*8 + kk*4 + m, 512 halfs per chunk.
// Element (lane,j): A[o = m*16 + (lane&15)][c = kk*32 + (lane>>4)*8 + j].
__global__ __launch_bounds__(256) void wtrans_k(
    const float* __restrict__ rh_w, const float* __restrict__ hl0_w,
    const float* __restrict__ hl_w, _Float16* __restrict__ wt)
{
    int t = blockIdx.x * 256 + threadIdx.x;
    if (t >= 8 * 4608) return;
    int layer = t / 4608;
    int r = t - layer * 4608;
    int lane = r & 63, ci = r >> 6;
    int m = ci & 3, kk = (ci >> 2) & 1, s = ci >> 3;
    int o = m * 16 + (lane & 15);
    int cb = kk * 32 + ((lane >> 4) & 3) * 8;
    const float* w; int O, CIN;
    if (layer < 4)      { w = rh_w + (size_t)layer * 61 * 61 * 9; O = 61; CIN = 61; }
    else if (layer == 4){ w = hl0_w;                              O = 64; CIN = 61; }
    else                { w = hl_w + (size_t)(layer - 5) * 64 * 64 * 9; O = 64; CIN = 64; }
    half8 v;
    #pragma unroll
    for (int j = 0; j < 8; ++j) {
        int c = cb + j;
        float f = (o < O && c < CIN) ? w[((size_t)o * CIN + c) * 9 + s] : 0.f;
        v[j] = (_Float16)f;
    }
    *(half8*)(wt + (size_t)layer * 36864 + (size_t)r * 8) = v;
}

// ---------------- MFMA implicit-GEMM conv, stride 1, 512x512 --------------
template<int O, int ACT>
__global__ __launch_bounds__(256, 2)
void conv_mfma_k(const float* __restrict__ in, const _Float16* __restrict__ wt,
                 const float* __restrict__ bias, float* __restrict__ out)
{
    __shared__ _Float16 __attribute__((aligned(16))) in_t[324 * 64];
    const int tid = threadIdx.x;
    const int l = tid & 63, wv = tid >> 6;
    const int px = l & 15, g = l >> 4;
    const int bx = blockIdx.x, by = blockIdx.y;
    const int iy0 = by * 16 - 1, ix0 = bx * 16 - 1;

    for (int c = 0; c < 64; ++c) {
        const float* inc = in + (size_t)c * HW_;
        for (int p = tid; p < 324; p += 256) {
            int iy = p / 18, ix = p - iy * 18;
            int gy = iy0 + iy, gx = ix0 + ix;
            float v = ((unsigned)gy < 512u && (unsigned)gx < 512u)
                          ? inc[gy * 512 + gx] : 0.f;
            in_t[p * 64 + (c ^ ((p & 7) << 3))] = (_Float16)v;
        }
    }
    __syncthreads();

    float bs[4][4];
    #pragma unroll
    for (int m = 0; m < 4; ++m)
        #pragma unroll
        for (int r = 0; r < 4; ++r) {
            int o = m * 16 + g * 4 + r;
            bs[m][r] = (o < O) ? bias[o] : 0.f;
        }

    f32x4 acc[4][4];
    #pragma unroll
    for (int m = 0; m < 4; ++m)
        #pragma unroll
        for (int f = 0; f < 4; ++f) acc[m][f] = (f32x4){0.f, 0.f, 0.f, 0.f};

    const _Float16* wb = wt + (size_t)l * 8;
    half8 aA[8], aB[8];
    #pragma unroll
    for (int q = 0; q < 8; ++q) aA[q] = *(const half8*)(wb + q * 512);

    #pragma unroll
    for (int s = 0; s < 9; ++s) {
        asm volatile("" ::: "memory");
        const half8* ac = (s & 1) ? aB : aA;
        half8*       an = (s & 1) ? aA : aB;
        if (s < 8) {
            #pragma unroll
            for (int q = 0; q < 8; ++q)
                an[q] = *(const half8*)(wb + ((s + 1) * 8 + q) * 512);
        }
        const int dy = s / 3, dx = s - dy * 3;
        #pragma unroll
        for (int f = 0; f < 4; ++f) {
            int ipix = (4 * wv + f + dy) * 18 + px + dx;
            int rb = ipix * 64, sw = (ipix & 7) << 3;
            #pragma unroll
            for (int kk = 0; kk < 2; ++kk) {
                half8 b = *(const half8*)&in_t[rb + ((kk * 32 + g * 8) ^ sw)];
                #pragma unroll
                for (int m = 0; m < 4; ++m)
                    acc[m][f] = __builtin_amdgcn_mfma_f32_16x16x32_f16(
                        ac[kk * 4 + m], b, acc[m][f], 0, 0, 0);
            }
        }
    }

    const int gx0 = bx * 16 + px;
    #pragma unroll
    for (int f = 0; f < 4; ++f) {
        const int gy = by * 16 + 4 * wv + f;
        float* orow = out + (size_t)gy * 512 + gx0;
        #pragma unroll
        for (int m = 0; m < 4; ++m)
            #pragma unroll
            for (int r = 0; r < 4; ++r) {
                int o = m * 16 + g * 4 + r;
                if (o < O) {
                    float v = acc[m][f][r] + bs[m][r];
                    if (ACT) v = fmaxf(v, 0.f);
                    orow[(size_t)o * HW_] = v;
                }
            }
    }
}

// ---------------- MFMA stride-2 conv + fused 2x2 maxpool ------------------
// 8x8 conv-out tile/block (grid Hout/8 x Hout/8), halo 17x17x64 in LDS fp16.
// Wave wv owns M-frag wv (16 out channels); N-frags f = conv rows 2f,2f+1.
// Pool via shfl_xor(1) + shfl_xor(8); lanes (l&9)==0 write pooled 4x4 tile.
__global__ __launch_bounds__(256, 2)
void conv_s2_pool_k(const float* __restrict__ in, int Hin,
                    const _Float16* __restrict__ wt,
                    const float* __restrict__ bias, float* __restrict__ out)
{
    const int Hp = Hin >> 2;
    __shared__ _Float16 __attribute__((aligned(16))) in_t[289 * 64];
    const int tid = threadIdx.x;
    const int l = tid & 63, wv = tid >> 6;
    const int n = l & 15, g = l >> 4;
    const int bx = blockIdx.x, by = blockIdx.y;
    const int iy0 = by * 16 - 1, ix0 = bx * 16 - 1;

    for (int c = 0; c < 64; ++c) {
        const float* inc = in + (size_t)c * Hin * Hin;
        for (int p = tid; p < 289; p += 256) {
            int iy = p / 17, ix = p - iy * 17;
            int gy = iy0 + iy, gx = ix0 + ix;
            float v = ((unsigned)gy < (unsigned)Hin && (unsigned)gx < (unsigned)Hin)
                          ? inc[(size_t)gy * Hin + gx] : 0.f;
            in_t[p * 64 + (c ^ ((p & 7) << 3))] = (_Float16)v;
        }
    }
    __syncthreads();

    float bs[4];
    #pragma unroll
    for (int r = 0; r < 4; ++r) bs[r] = bias[wv * 16 + g * 4 + r];

    f32x4 acc[4];
    #pragma unroll
    for (int f = 0; f < 4; ++f) acc[f] = (f32x4){0.f, 0.f, 0.f, 0.f};

    const int py_lo = n >> 3, pxc = n & 7;   // within-tile conv coords
    #pragma unroll
    for (int s = 0; s < 9; ++s) {
        const int dy = s / 3, dx = s - dy * 3;
        half8 a[2];
        #pragma unroll
        for (int kk = 0; kk < 2; ++kk)
            a[kk] = *(const half8*)(wt + (size_t)(s * 8 + kk * 4 + wv) * 512 + l * 8);
        #pragma unroll
        for (int f = 0; f < 4; ++f) {
            int py = 2 * f + py_lo;
            int ipix = (2 * py + dy) * 17 + 2 * pxc + dx;
            int rb = ipix * 64, sw = (ipix & 7) << 3;
            #pragma unroll
            for (int kk = 0; kk < 2; ++kk) {
                half8 b = *(const half8*)&in_t[rb + ((kk * 32 + g * 8) ^ sw)];
                acc[f] = __builtin_amdgcn_mfma_f32_16x16x32_f16(a[kk], b, acc[f], 0, 0, 0);
            }
        }
    }

    #pragma unroll
    for (int f = 0; f < 4; ++f)
        #pragma unroll
        for (int r = 0; r < 4; ++r) {
            float v = fmaxf(acc[f][r] + bs[r], 0.f);       // relu
            v = fmaxf(v, __shfl_xor(v, 1));                // horizontal pair
            v = fmaxf(v, __shfl_xor(v, 8));                // vertical pair
            if ((l & 9) == 0) {
                int o = wv * 16 + g * 4 + r;
                int gpy = by * 4 + f, gpx = bx * 4 + (n >> 1);
                out[((size_t)o * Hp + gpy) * Hp + gpx] = v;
            }
        }
}

// ---------------- tail ----------------------------------------------------
__global__ void meanlin_k(const float* __restrict__ h,
                          const float* __restrict__ lw,
                          const float* __restrict__ lb,
                          float* __restrict__ wm)
{
    __shared__ float g[64];
    int t = threadIdx.x;
    if (t < 64) {
        float s = 0.f;
        for (int p = 0; p < 64; ++p) s += h[t * 64 + p];
        g[t] = s * (1.f / 64.f);
    }
    __syncthreads();
    if (t < 30) {
        float s = lb[t];
        for (int c = 0; c < 64; ++c) s = fmaf(g[c], lw[t * 64 + c], s);
        wm[t] = s;
    }
}

__global__ __launch_bounds__(256)
void final_k(const float* __restrict__ I3, const float* __restrict__ wm,
             float* __restrict__ out)
{
    __shared__ float W[30];
    if (threadIdx.x < 30) W[threadIdx.x] = wm[threadIdx.x];
    __syncthreads();
    const int HW = 512 * 512;
    for (int i = blockIdx.x * blockDim.x + threadIdx.x; i < HW;
         i += gridDim.x * blockDim.x) {
        float r = I3[i], g = I3[HW + i], b = I3[2 * HW + i];
        float f[10] = { r * r, r * g, r * b, r, g * g, g * b, g, b * b, b, 1.f };
        #pragma unroll
        for (int o = 0; o < 3; ++o) {
            float s = 0.f;
            #pragma unroll
            for (int k = 0; k < 10; ++k) s = fmaf(W[o * 10 + k], f[k], s);
            out[(size_t)o * HW + i] = s;
        }
    }
}

extern "C" void kernel_launch(void* const* d_in, const int* in_sizes, int n_in,
                              void* d_out, int out_size, void* d_ws, size_t ws_size,
                              hipStream_t stream)
{
    const float* x      = (const float*)d_in[0];
    const float* low0_w = (const float*)d_in[1];
    const float* low0_b = (const float*)d_in[2];
    const float* rh_w   = (const float*)d_in[3];   // (4,61,61,3,3)
    const float* rh_b   = (const float*)d_in[4];   // (4,61)
    const float* lh_w   = (const float*)d_in[5];   // (4,3,3,3,3)
    const float* lh_b   = (const float*)d_in[6];   // (4,3)
    const float* hl0_w  = (const float*)d_in[7];   // (64,61,3,3)
    const float* hl0_b  = (const float*)d_in[8];   // (64,)
    const float* hl_w   = (const float*)d_in[9];   // (3,64,64,3,3)
    const float* hl_b   = (const float*)d_in[10];  // (3,64)
    const float* lin_w  = (const float*)d_in[11];  // (30,64)
    const float* lin_b  = (const float*)d_in[12];  // (30,)
    float* out = (float*)d_out;

    const size_t HW = 512 * 512;
    float* A  = (float*)d_ws;                      // 64*HW
    float* B  = A + 64 * HW;                       // 64*HW
    float* P0 = B + 64 * HW;                       // 64*128*128
    float* P1 = P0 + (size_t)64 * 128 * 128;       // 64*32*32
    float* P2 = P1 + (size_t)64 * 32 * 32;         // 64*8*8
    float* WM = P2 + (size_t)64 * 8 * 8;           // 30 (padded to 32)
    _Float16* WT = (_Float16*)(WM + 32);           // 8*36864 halfs

    dim3 blk(256);
    dim3 g512(32, 32, 1);
    dim3 gmf(32, 32, 1);

    // pre-transform all conv weights to fragment-linear fp16
    wtrans_k<<<dim3(144), blk, 0, stream>>>(rh_w, hl0_w, hl_w, WT);

    // I = conv(x)  (fp32 VALU, Cin=3 — keeps I3 path exact)
    conv3x3_k<64, 1, 0><<<g512, blk, 0, stream>>>(x, 3, 512, 512,
                                                  low0_w, low0_b, A, 512, 512);

    float* cur = A; float* nxt = B;
    for (int i = 0; i < 4; ++i) {
        conv_mfma_k<61, 1><<<gmf, blk, 0, stream>>>(
            cur, WT + (size_t)i * 36864, rh_b + i * 61, nxt);
        conv3x3_k<3, 1, 2><<<g512, blk, 0, stream>>>(
            cur + 61 * HW, 3, 512, 512, lh_w + (size_t)i * 81, lh_b + i * 3,
            nxt + 61 * HW, 512, 512);
        float* t = cur; cur = nxt; nxt = t;
    }
    // final I is in cur == A

    // h = conv(I[:, :61]) -> 64ch
    conv_mfma_k<64, 0><<<gmf, blk, 0, stream>>>(
        cur, WT + (size_t)4 * 36864, hl0_b, nxt);

    // 3 fused stride-2 conv + relu + 2x2 maxpool stages
    conv_s2_pool_k<<<dim3(32, 32), blk, 0, stream>>>(
        nxt, 512, WT + (size_t)5 * 36864, hl_b, P0);
    conv_s2_pool_k<<<dim3(8, 8), blk, 0, stream>>>(
        P0, 128, WT + (size_t)6 * 36864, hl_b + 64, P1);
    conv_s2_pool_k<<<dim3(2, 2), blk, 0, stream>>>(
        P1, 32, WT + (size_t)7 * 36864, hl_b + 128, P2);

    // g = mean(h); Wp = g @ lin_w.T + lin_b
    meanlin_k<<<dim3(1), dim3(64), 0, stream>>>(P2, lin_w, lin_b, WM);

    // out = einsum('ok,bkhw->bohw', Wm, feats(I[:,61:]))
    final_k<<<dim3(2048), blk, 0, stream>>>(cur + 61 * HW, WM, out);
}

// Round 4
// 291.420 us; speedup vs baseline: 11.2659x; 2.8651x over previous
//
#include <hip/hip_runtime.h>
#include <cstdint>

typedef _Float16 half8 __attribute__((ext_vector_type(8)));
typedef float f32x4 __attribute__((ext_vector_type(4)));

#define HW_ (512*512)

// ---------------- fp32 VALU direct conv (kept for lh 3->3 tanh) -----------
template<int COUT, int STRIDE, int ACT>
__global__ __launch_bounds__(256)
void conv3x3_k(const float* __restrict__ in, int Cin, int Hin, int Win,
               const float* __restrict__ w, const float* __restrict__ bias,
               float* __restrict__ out, int Hout, int Wout)
{
    constexpr int T = 16;
    constexpr int SPAN = (T - 1) * STRIDE + 3;
    __shared__ float tile[SPAN * SPAN];

    const int tx = threadIdx.x & 15;
    const int ty = threadIdx.x >> 4;
    const int ox = blockIdx.x * T + tx;
    const int oy = blockIdx.y * T + ty;
    const int ix0 = blockIdx.x * T * STRIDE - 1;
    const int iy0 = blockIdx.y * T * STRIDE - 1;

    float acc[COUT];
    #pragma unroll
    for (int o = 0; o < COUT; ++o) acc[o] = bias[o];

    for (int c = 0; c < Cin; ++c) {
        const float* inc = in + (size_t)c * Hin * Win;
        __syncthreads();
        for (int idx = threadIdx.x; idx < SPAN * SPAN; idx += 256) {
            int yy = idx / SPAN, xx = idx - yy * SPAN;
            int gy = iy0 + yy, gx = ix0 + xx;
            float v = 0.f;
            if ((unsigned)gy < (unsigned)Hin && (unsigned)gx < (unsigned)Win)
                v = inc[(size_t)gy * Win + gx];
            tile[idx] = v;
        }
        __syncthreads();

        float p[9];
        #pragma unroll
        for (int dy = 0; dy < 3; ++dy)
            #pragma unroll
            for (int dx = 0; dx < 3; ++dx)
                p[dy * 3 + dx] = tile[(ty * STRIDE + dy) * SPAN + tx * STRIDE + dx];

        const float* wc = w + c * 9;
        #pragma unroll
        for (int o = 0; o < COUT; ++o) {
            const float* wo = wc + (size_t)o * Cin * 9;
            float a = acc[o];
            #pragma unroll
            for (int k = 0; k < 9; ++k) a = fmaf(p[k], wo[k], a);
            acc[o] = a;
        }
    }

    if (ox < Wout && oy < Hout) {
        const size_t pix = (size_t)oy * Wout + ox;
        #pragma unroll
        for (int o = 0; o < COUT; ++o) {
            float v = acc[o];
            if (ACT == 1) v = fmaxf(v, 0.f);
            else if (ACT == 2) v = tanhf(v);
            out[(size_t)o * Hout * Wout + pix] = v;
        }
    }
}

// ---------------- weight transform: fp32 -> frag-linear fp16 --------------
// 8 layers: 0-3 rh (O=61,CIN=61), 4 hl0 (O=64,CIN=61), 5-7 hl (O=64,CIN=64).
// Per layer 36864 halfs: chunk ci = s*8 + kk*4 + m, 512 halfs per chunk.
// Element (lane,j): A[o = m*16 + (lane&15)][c = kk*32 + (lane>>4)*8 + j].
__global__ __launch_bounds__(256) void wtrans_k(
    const float* __restrict__ rh_w, const float* __restrict__ hl0_w,
    const float* __restrict__ hl_w, _Float16* __restrict__ wt)
{
    int t = blockIdx.x * 256 + threadIdx.x;
    if (t >= 8 * 4608) return;
    int layer = t / 4608;
    int r = t - layer * 4608;
    int lane = r & 63, ci = r >> 6;
    int m = ci & 3, kk = (ci >> 2) & 1, s = ci >> 3;
    int o = m * 16 + (lane & 15);
    int cb = kk * 32 + ((lane >> 4) & 3) * 8;
    const float* w; int O, CIN;
    if (layer < 4)      { w = rh_w + (size_t)layer * 61 * 61 * 9; O = 61; CIN = 61; }
    else if (layer == 4){ w = hl0_w;                              O = 64; CIN = 61; }
    else                { w = hl_w + (size_t)(layer - 5) * 64 * 64 * 9; O = 64; CIN = 64; }
    half8 v;
    #pragma unroll
    for (int j = 0; j < 8; ++j) {
        int c = cb + j;
        float f = (o < O && c < CIN) ? w[((size_t)o * CIN + c) * 9 + s] : 0.f;
        v[j] = (_Float16)f;
    }
    *(half8*)(wt + (size_t)layer * 36864 + (size_t)r * 8) = v;
}

// ---------------- low0: 3->64 fp32 conv, writes interleaved fp16 + L ------
// grid (32,32,4): z = 16-channel output group. Also writes channels 61..63
// as fp32 planes to L (exact path for lh/tanh chain).
__global__ __launch_bounds__(256)
void low0_k(const float* __restrict__ x, const float* __restrict__ w,
            const float* __restrict__ bias, _Float16* __restrict__ M,
            float* __restrict__ L)
{
    __shared__ float tile[3 * 324];
    const int tx = threadIdx.x & 15, ty = threadIdx.x >> 4;
    const int bx = blockIdx.x, by = blockIdx.y, z = blockIdx.z;
    const int ox = bx * 16 + tx, oy = by * 16 + ty;
    const int ix0 = bx * 16 - 1, iy0 = by * 16 - 1;

    for (int i = threadIdx.x; i < 3 * 324; i += 256) {
        int c = i / 324, p = i - c * 324;
        int iy = p / 18, ix = p - iy * 18;
        int gy = iy0 + iy, gx = ix0 + ix;
        float v = 0.f;
        if ((unsigned)gy < 512u && (unsigned)gx < 512u)
            v = x[(size_t)c * HW_ + (size_t)gy * 512 + gx];
        tile[i] = v;
    }
    __syncthreads();

    float p9[3][9];
    #pragma unroll
    for (int c = 0; c < 3; ++c)
        #pragma unroll
        for (int dy = 0; dy < 3; ++dy)
            #pragma unroll
            for (int dx = 0; dx < 3; ++dx)
                p9[c][dy * 3 + dx] = tile[c * 324 + (ty + dy) * 18 + tx + dx];

    float acc[16];
    #pragma unroll
    for (int o = 0; o < 16; ++o) {
        int oc = z * 16 + o;
        float a = bias[oc];
        const float* wo = w + (size_t)oc * 27;
        #pragma unroll
        for (int c = 0; c < 3; ++c)
            #pragma unroll
            for (int k = 0; k < 9; ++k)
                a = fmaf(p9[c][k], wo[c * 9 + k], a);
        acc[o] = a;
    }

    const size_t pix = (size_t)oy * 512 + ox;
    half8 h0, h1;
    #pragma unroll
    for (int o = 0; o < 8; ++o) { h0[o] = (_Float16)acc[o]; h1[o] = (_Float16)acc[8 + o]; }
    _Float16* orow = M + pix * 64 + z * 16;
    *(half8*)(orow)     = h0;
    *(half8*)(orow + 8) = h1;
    if (z == 3) {
        #pragma unroll
        for (int o = 13; o < 16; ++o)
            L[(size_t)(o - 13) * HW_ + pix] = acc[o];
    }
}

// ---------------- MFMA implicit-GEMM conv, stride 1, 512x512 --------------
// IO: fp16 channel-interleaved [pixel][64]. LDS [p][c ^ ((p&7)<<3)].
// Staging: linear 16-B LDS writes; swizzle folded into SOURCE chunk index.
template<int O, int ACT>
__global__ __launch_bounds__(256, 2)
void conv_mfma_k(const _Float16* __restrict__ in, const _Float16* __restrict__ wt,
                 const float* __restrict__ bias, _Float16* __restrict__ out)
{
    __shared__ _Float16 __attribute__((aligned(16))) in_t[324 * 64];
    const int tid = threadIdx.x;
    const int l = tid & 63, wv = tid >> 6;
    const int px = l & 15, g = l >> 4;
    const int bx = blockIdx.x, by = blockIdx.y;
    const int iy0 = by * 16 - 1, ix0 = bx * 16 - 1;

    for (int i = tid; i < 324 * 8; i += 256) {
        int p = i >> 3, jl = i & 7;
        int iy = p / 18, ix = p - iy * 18;
        int gy = iy0 + iy, gx = ix0 + ix;
        int j = jl ^ (p & 7);
        half8 v = (half8)(_Float16)0.f;
        if ((unsigned)gy < 512u && (unsigned)gx < 512u)
            v = *(const half8*)(in + ((size_t)gy * 512 + gx) * 64 + j * 8);
        *(half8*)&in_t[p * 64 + jl * 8] = v;
    }
    __syncthreads();

    float bs[4][4];
    #pragma unroll
    for (int m = 0; m < 4; ++m)
        #pragma unroll
        for (int r = 0; r < 4; ++r) {
            int o = m * 16 + g * 4 + r;
            bs[m][r] = (o < O) ? bias[o] : 0.f;
        }

    f32x4 acc[4][4];
    #pragma unroll
    for (int m = 0; m < 4; ++m)
        #pragma unroll
        for (int f = 0; f < 4; ++f) acc[m][f] = (f32x4){0.f, 0.f, 0.f, 0.f};

    const _Float16* wb = wt + (size_t)l * 8;
    half8 aA[8], aB[8];
    #pragma unroll
    for (int q = 0; q < 8; ++q) aA[q] = *(const half8*)(wb + q * 512);

    #pragma unroll
    for (int s = 0; s < 9; ++s) {
        asm volatile("" ::: "memory");
        const half8* ac = (s & 1) ? aB : aA;
        half8*       an = (s & 1) ? aA : aB;
        if (s < 8) {
            #pragma unroll
            for (int q = 0; q < 8; ++q)
                an[q] = *(const half8*)(wb + ((s + 1) * 8 + q) * 512);
        }
        const int dy = s / 3, dx = s - dy * 3;
        #pragma unroll
        for (int f = 0; f < 4; ++f) {
            int ipix = (4 * wv + f + dy) * 18 + px + dx;
            int rb = ipix * 64, sw = (ipix & 7) << 3;
            #pragma unroll
            for (int kk = 0; kk < 2; ++kk) {
                half8 b = *(const half8*)&in_t[rb + ((kk * 32 + g * 8) ^ sw)];
                #pragma unroll
                for (int m = 0; m < 4; ++m)
                    acc[m][f] = __builtin_amdgcn_mfma_f32_16x16x32_f16(
                        ac[kk * 4 + m], b, acc[m][f], 0, 0, 0);
            }
        }
    }

    // Epilogue -> fp16 interleaved. C-layout: lane(px,g) reg r -> channel
    // m*16+g*4+r. Pair lanes g^1 via shfl_xor(16) to form 8-channel chunks.
    const int gx0 = bx * 16 + px;
    const int gpair = g >> 1;
    #pragma unroll
    for (int f = 0; f < 4; ++f) {
        const int gy = by * 16 + 4 * wv + f;
        _Float16* orow = out + ((size_t)gy * 512 + gx0) * 64;
        uint2 mine[4], theirs[4];
        #pragma unroll
        for (int m = 0; m < 4; ++m) {
            union { _Float16 h[4]; uint2 u; } pk;
            #pragma unroll
            for (int r = 0; r < 4; ++r) {
                int o = m * 16 + g * 4 + r;
                float v = acc[m][f][r] + bs[m][r];
                if (ACT) v = fmaxf(v, 0.f);
                pk.h[r] = (o < O) ? (_Float16)v : (_Float16)0.f;
            }
            mine[m] = pk.u;
            theirs[m].x = __shfl_xor((int)pk.u.x, 16);
            theirs[m].y = __shfl_xor((int)pk.u.y, 16);
        }
        #pragma unroll
        for (int mm = 0; mm < 2; ++mm) {
            int m = (g & 1) * 2 + mm;
            union { uint2 u[2]; half8 v; } st;
            if ((g & 1) == 0) { st.u[0] = mine[m];   st.u[1] = theirs[m]; }
            else              { st.u[0] = theirs[m]; st.u[1] = mine[m];   }
            *(half8*)(orow + m * 16 + gpair * 8) = st.v;
        }
    }
}

// ---------------- MFMA stride-2 conv + relu + fused 2x2 maxpool -----------
// fp16 interleaved in; out fp16 interleaved (FP32OUT=0) or fp32 interleaved.
template<int FP32OUT>
__global__ __launch_bounds__(256, 2)
void conv_s2_pool_k(const _Float16* __restrict__ in, int Hin,
                    const _Float16* __restrict__ wt,
                    const float* __restrict__ bias, void* __restrict__ outv)
{
    const int Hp = Hin >> 2;
    __shared__ _Float16 __attribute__((aligned(16))) in_t[289 * 64];
    const int tid = threadIdx.x;
    const int l = tid & 63, wv = tid >> 6;
    const int n = l & 15, g = l >> 4;
    const int bx = blockIdx.x, by = blockIdx.y;
    const int iy0 = by * 16 - 1, ix0 = bx * 16 - 1;

    for (int i = tid; i < 289 * 8; i += 256) {
        int p = i >> 3, jl = i & 7;
        int iy = p / 17, ix = p - iy * 17;
        int gy = iy0 + iy, gx = ix0 + ix;
        int j = jl ^ (p & 7);
        half8 v = (half8)(_Float16)0.f;
        if ((unsigned)gy < (unsigned)Hin && (unsigned)gx < (unsigned)Hin)
            v = *(const half8*)(in + ((size_t)gy * Hin + gx) * 64 + j * 8);
        *(half8*)&in_t[p * 64 + jl * 8] = v;
    }
    __syncthreads();

    float bs[4];
    #pragma unroll
    for (int r = 0; r < 4; ++r) bs[r] = bias[wv * 16 + g * 4 + r];

    f32x4 acc[4];
    #pragma unroll
    for (int f = 0; f < 4; ++f) acc[f] = (f32x4){0.f, 0.f, 0.f, 0.f};

    const int py_lo = n >> 3, pxc = n & 7;
    #pragma unroll
    for (int s = 0; s < 9; ++s) {
        const int dy = s / 3, dx = s - dy * 3;
        half8 a[2];
        #pragma unroll
        for (int kk = 0; kk < 2; ++kk)
            a[kk] = *(const half8*)(wt + (size_t)(s * 8 + kk * 4 + wv) * 512 + l * 8);
        #pragma unroll
        for (int f = 0; f < 4; ++f) {
            int py = 2 * f + py_lo;
            int ipix = (2 * py + dy) * 17 + 2 * pxc + dx;
            int rb = ipix * 64, sw = (ipix & 7) << 3;
            #pragma unroll
            for (int kk = 0; kk < 2; ++kk) {
                half8 b = *(const half8*)&in_t[rb + ((kk * 32 + g * 8) ^ sw)];
                acc[f] = __builtin_amdgcn_mfma_f32_16x16x32_f16(a[kk], b, acc[f], 0, 0, 0);
            }
        }
    }

    #pragma unroll
    for (int f = 0; f < 4; ++f)
        #pragma unroll
        for (int r = 0; r < 4; ++r) {
            float v = fmaxf(acc[f][r] + bs[r], 0.f);
            v = fmaxf(v, __shfl_xor(v, 1));
            v = fmaxf(v, __shfl_xor(v, 8));
            if ((l & 9) == 0) {
                int o = wv * 16 + g * 4 + r;
                size_t pp = ((size_t)(by * 4 + f) * Hp + bx * 4 + (n >> 1)) * 64 + o;
                if (FP32OUT) ((float*)outv)[pp] = v;
                else         ((_Float16*)outv)[pp] = (_Float16)v;
            }
        }
}

// ---------------- tail ----------------------------------------------------
__global__ void meanlin_k(const float* __restrict__ h,   // [64pix][64ch] f32
                          const float* __restrict__ lw,
                          const float* __restrict__ lb,
                          float* __restrict__ wm)
{
    __shared__ float g[64];
    int t = threadIdx.x;
    if (t < 64) {
        float s = 0.f;
        for (int p = 0; p < 64; ++p) s += h[p * 64 + t];
        g[t] = s * (1.f / 64.f);
    }
    __syncthreads();
    if (t < 30) {
        float s = lb[t];
        for (int c = 0; c < 64; ++c) s = fmaf(g[c], lw[t * 64 + c], s);
        wm[t] = s;
    }
}

__global__ __launch_bounds__(256)
void final_k(const float* __restrict__ I3, const float* __restrict__ wm,
             float* __restrict__ out)
{
    __shared__ float W[30];
    if (threadIdx.x < 30) W[threadIdx.x] = wm[threadIdx.x];
    __syncthreads();
    const int HW = 512 * 512;
    for (int i = blockIdx.x * blockDim.x + threadIdx.x; i < HW;
         i += gridDim.x * blockDim.x) {
        float r = I3[i], g = I3[HW + i], b = I3[2 * HW + i];
        float f[10] = { r * r, r * g, r * b, r, g * g, g * b, g, b * b, b, 1.f };
        #pragma unroll
        for (int o = 0; o < 3; ++o) {
            float s = 0.f;
            #pragma unroll
            for (int k = 0; k < 10; ++k) s = fmaf(W[o * 10 + k], f[k], s);
            out[(size_t)o * HW + i] = s;
        }
    }
}

extern "C" void kernel_launch(void* const* d_in, const int* in_sizes, int n_in,
                              void* d_out, int out_size, void* d_ws, size_t ws_size,
                              hipStream_t stream)
{
    const float* x      = (const float*)d_in[0];
    const float* low0_w = (const float*)d_in[1];
    const float* low0_b = (const float*)d_in[2];
    const float* rh_w   = (const float*)d_in[3];
    const float* rh_b   = (const float*)d_in[4];
    const float* lh_w   = (const float*)d_in[5];
    const float* lh_b   = (const float*)d_in[6];
    const float* hl0_w  = (const float*)d_in[7];
    const float* hl0_b  = (const float*)d_in[8];
    const float* hl_w   = (const float*)d_in[9];
    const float* hl_b   = (const float*)d_in[10];
    const float* lin_w  = (const float*)d_in[11];
    const float* lin_b  = (const float*)d_in[12];
    float* out = (float*)d_out;

    const size_t HW = 512 * 512;
    _Float16* M0 = (_Float16*)d_ws;                       // [HW][64] fp16
    _Float16* M1 = M0 + (size_t)64 * HW;
    _Float16* P0 = M1 + (size_t)64 * HW;                  // [128*128][64] fp16
    _Float16* P1 = P0 + (size_t)64 * 128 * 128;           // [32*32][64] fp16
    float*    P2 = (float*)(P1 + (size_t)64 * 32 * 32);   // [8*8][64] fp32
    float*    L0 = P2 + 64 * 64;                          // 3 planes fp32
    float*    L1 = L0 + (size_t)3 * HW;
    float*    WM = L1 + (size_t)3 * HW;                   // 30 (pad 32)
    _Float16* WT = (_Float16*)(WM + 32);                  // 8*36864 halfs

    dim3 blk(256);
    dim3 g512(32, 32, 1);

    wtrans_k<<<dim3(144), blk, 0, stream>>>(rh_w, hl0_w, hl_w, WT);

    // I = conv(x): fp16 interleaved M0 (all 64ch) + exact fp32 ch61..63 -> L0
    low0_k<<<dim3(32, 32, 4), blk, 0, stream>>>(x, low0_w, low0_b, M0, L0);

    _Float16* cur = M0; _Float16* nxt = M1;
    float* Lc = L0; float* Ln = L1;
    for (int i = 0; i < 4; ++i) {
        conv_mfma_k<61, 1><<<g512, blk, 0, stream>>>(
            cur, WT + (size_t)i * 36864, rh_b + i * 61, nxt);
        conv3x3_k<3, 1, 2><<<g512, blk, 0, stream>>>(
            Lc, 3, 512, 512, lh_w + (size_t)i * 81, lh_b + i * 3, Ln, 512, 512);
        _Float16* t = cur; cur = nxt; nxt = t;
        float* tl = Lc; Lc = Ln; Ln = tl;
    }

    // h = conv(I[:, :61]) -> 64ch fp16 interleaved
    conv_mfma_k<64, 0><<<g512, blk, 0, stream>>>(
        cur, WT + (size_t)4 * 36864, hl0_b, nxt);

    conv_s2_pool_k<0><<<dim3(32, 32), blk, 0, stream>>>(
        nxt, 512, WT + (size_t)5 * 36864, hl_b, (void*)P0);
    conv_s2_pool_k<0><<<dim3(8, 8), blk, 0, stream>>>(
        P0, 128, WT + (size_t)6 * 36864, hl_b + 64, (void*)P1);
    conv_s2_pool_k<1><<<dim3(2, 2), blk, 0, stream>>>(
        P1, 32, WT + (size_t)7 * 36864, hl_b + 128, (void*)P2);

    meanlin_k<<<dim3(1), dim3(64), 0, stream>>>(P2, lin_w, lin_b, WM);

    final_k<<<dim3(2048), blk, 0, stream>>>(Lc, WM, out);
}

// Round 5
// 285.438 us; speedup vs baseline: 11.5020x; 1.0210x over previous
//
#include <hip/hip_runtime.h>
#include <cstdint>

typedef _Float16 half8 __attribute__((ext_vector_type(8)));
typedef float f32x4 __attribute__((ext_vector_type(4)));

#define HW_ (512*512)

// ---------------- weight transform: fp32 -> frag-linear fp16 --------------
// 8 layers: 0-3 rh (O=61,CIN=61), 4 hl0 (O=64,CIN=61), 5-7 hl (O=64,CIN=64).
// Per layer 36864 halfs: chunk ci = s*8 + kk*4 + m, 512 halfs per chunk.
// Element (lane,j): A[o = m*16 + (lane&15)][c = kk*32 + (lane>>4)*8 + j].
// Block 0 also zeroes the 32-half guard region ZG (OOB staging target).
__global__ __launch_bounds__(256) void wtrans_k(
    const float* __restrict__ rh_w, const float* __restrict__ hl0_w,
    const float* __restrict__ hl_w, _Float16* __restrict__ wt,
    _Float16* __restrict__ zg)
{
    if (blockIdx.x == 0 && threadIdx.x < 32) zg[threadIdx.x] = (_Float16)0.f;
    int t = blockIdx.x * 256 + threadIdx.x;
    if (t >= 8 * 4608) return;
    int layer = t / 4608;
    int r = t - layer * 4608;
    int lane = r & 63, ci = r >> 6;
    int m = ci & 3, kk = (ci >> 2) & 1, s = ci >> 3;
    int o = m * 16 + (lane & 15);
    int cb = kk * 32 + ((lane >> 4) & 3) * 8;
    const float* w; int O, CIN;
    if (layer < 4)      { w = rh_w + (size_t)layer * 61 * 61 * 9; O = 61; CIN = 61; }
    else if (layer == 4){ w = hl0_w;                              O = 64; CIN = 61; }
    else                { w = hl_w + (size_t)(layer - 5) * 64 * 64 * 9; O = 64; CIN = 64; }
    half8 v;
    #pragma unroll
    for (int j = 0; j < 8; ++j) {
        int c = cb + j;
        float f = (o < O && c < CIN) ? w[((size_t)o * CIN + c) * 9 + s] : 0.f;
        v[j] = (_Float16)f;
    }
    *(half8*)(wt + (size_t)layer * 36864 + (size_t)r * 8) = v;
}

// ---------------- low0: 3->64 fp32 conv, writes interleaved fp16 + L ------
__global__ __launch_bounds__(256)
void low0_k(const float* __restrict__ x, const float* __restrict__ w,
            const float* __restrict__ bias, _Float16* __restrict__ M,
            float* __restrict__ L)
{
    __shared__ float tile[3 * 324];
    const int tx = threadIdx.x & 15, ty = threadIdx.x >> 4;
    const int bx = blockIdx.x, by = blockIdx.y, z = blockIdx.z;
    const int ox = bx * 16 + tx, oy = by * 16 + ty;
    const int ix0 = bx * 16 - 1, iy0 = by * 16 - 1;

    for (int i = threadIdx.x; i < 3 * 324; i += 256) {
        int c = i / 324, p = i - c * 324;
        int iy = p / 18, ix = p - iy * 18;
        int gy = iy0 + iy, gx = ix0 + ix;
        float v = 0.f;
        if ((unsigned)gy < 512u && (unsigned)gx < 512u)
            v = x[(size_t)c * HW_ + (size_t)gy * 512 + gx];
        tile[i] = v;
    }
    __syncthreads();

    float p9[3][9];
    #pragma unroll
    for (int c = 0; c < 3; ++c)
        #pragma unroll
        for (int dy = 0; dy < 3; ++dy)
            #pragma unroll
            for (int dx = 0; dx < 3; ++dx)
                p9[c][dy * 3 + dx] = tile[c * 324 + (ty + dy) * 18 + tx + dx];

    float acc[16];
    #pragma unroll
    for (int o = 0; o < 16; ++o) {
        int oc = z * 16 + o;
        float a = bias[oc];
        const float* wo = w + (size_t)oc * 27;
        #pragma unroll
        for (int c = 0; c < 3; ++c)
            #pragma unroll
            for (int k = 0; k < 9; ++k)
                a = fmaf(p9[c][k], wo[c * 9 + k], a);
        acc[o] = a;
    }

    const size_t pix = (size_t)oy * 512 + ox;
    half8 h0, h1;
    #pragma unroll
    for (int o = 0; o < 8; ++o) { h0[o] = (_Float16)acc[o]; h1[o] = (_Float16)acc[8 + o]; }
    _Float16* orow = M + pix * 64 + z * 16;
    *(half8*)(orow)     = h0;
    *(half8*)(orow + 8) = h1;
    if (z == 3) {
        #pragma unroll
        for (int o = 13; o < 16; ++o)
            L[(size_t)(o - 13) * HW_ + pix] = acc[o];
    }
}

// ---------------- MFMA implicit-GEMM conv, stride 1, 512x512 --------------
// IO: fp16 channel-interleaved [pixel][64]. LDS [p][c ^ ((p&7)<<3)].
// Staging via global_load_lds width=16: LDS dest linear (chunk i -> i*16B,
// wave-uniform base + lane*16), swizzle folded into per-lane SOURCE index;
// OOB lanes read the zero guard zg. DOLH: fused 3->3 tanh conv (lh chain).
template<int O, int ACT, int DOLH>
__global__ __launch_bounds__(256, 3)
void conv_mfma_k(const _Float16* __restrict__ in, const _Float16* __restrict__ wt,
                 const float* __restrict__ bias, _Float16* __restrict__ out,
                 const float* __restrict__ L_in, const float* __restrict__ lhw,
                 const float* __restrict__ lhb, float* __restrict__ L_out,
                 const _Float16* __restrict__ zg)
{
    __shared__ _Float16 __attribute__((aligned(16))) in_t[2816 * 8]; // 45056 B
    __shared__ float lh_t[3 * 324];
    const int tid = threadIdx.x;
    const int l = tid & 63, wv = tid >> 6;
    const int px = l & 15, g = l >> 4;
    const int bx = blockIdx.x, by = blockIdx.y;
    const int iy0 = by * 16 - 1, ix0 = bx * 16 - 1;

    #pragma unroll
    for (int k = 0; k < 11; ++k) {
        int i = tid + (k << 8);
        int p = i >> 3, jl = i & 7;
        int iy = p / 18, ix = p - iy * 18;
        int gy = iy0 + iy, gx = ix0 + ix;
        int j = jl ^ (p & 7);
        const _Float16* src =
            (p < 324 && (unsigned)gy < 512u && (unsigned)gx < 512u)
                ? in + ((size_t)gy * 512 + gx) * 64 + j * 8 : zg;
        __builtin_amdgcn_global_load_lds(
            (const __attribute__((address_space(1))) void*)src,
            (__attribute__((address_space(3))) void*)(in_t + (size_t)(tid - l + (k << 8)) * 8),
            16, 0, 0);
    }
    if (DOLH) {
        for (int i = tid; i < 3 * 324; i += 256) {
            int c = i / 324, p = i - c * 324;
            int iy = p / 18, ix = p - iy * 18;
            int gy = iy0 + iy, gx = ix0 + ix;
            float v = 0.f;
            if ((unsigned)gy < 512u && (unsigned)gx < 512u)
                v = L_in[(size_t)c * HW_ + (size_t)gy * 512 + gx];
            lh_t[i] = v;
        }
    }
    __syncthreads();

    float bs[4][4];
    #pragma unroll
    for (int m = 0; m < 4; ++m)
        #pragma unroll
        for (int r = 0; r < 4; ++r) {
            int o = m * 16 + g * 4 + r;
            bs[m][r] = (o < O) ? bias[o] : 0.f;
        }

    f32x4 acc[4][4];
    #pragma unroll
    for (int m = 0; m < 4; ++m)
        #pragma unroll
        for (int f = 0; f < 4; ++f) acc[m][f] = (f32x4){0.f, 0.f, 0.f, 0.f};

    const _Float16* wb = wt + (size_t)l * 8;
    half8 aA[8], aB[8];
    #pragma unroll
    for (int q = 0; q < 8; ++q) aA[q] = *(const half8*)(wb + q * 512);

    #pragma unroll
    for (int s = 0; s < 9; ++s) {
        asm volatile("" ::: "memory");
        const half8* ac = (s & 1) ? aB : aA;
        half8*       an = (s & 1) ? aA : aB;
        if (s < 8) {
            #pragma unroll
            for (int q = 0; q < 8; ++q)
                an[q] = *(const half8*)(wb + ((s + 1) * 8 + q) * 512);
        }
        const int dy = s / 3, dx = s - dy * 3;
        #pragma unroll
        for (int f = 0; f < 4; ++f) {
            int ipix = (4 * wv + f + dy) * 18 + px + dx;
            int rb = ipix * 64, sw = (ipix & 7) << 3;
            #pragma unroll
            for (int kk = 0; kk < 2; ++kk) {
                half8 b = *(const half8*)&in_t[rb + ((kk * 32 + g * 8) ^ sw)];
                #pragma unroll
                for (int m = 0; m < 4; ++m)
                    acc[m][f] = __builtin_amdgcn_mfma_f32_16x16x32_f16(
                        ac[kk * 4 + m], b, acc[m][f], 0, 0, 0);
            }
        }
    }

    // fused lh: 3->3 fp32 conv + tanh on exact path (independent chain)
    if (DOLH) {
        const int tx = tid & 15, ty = tid >> 4;
        const size_t pix = (size_t)(by * 16 + ty) * 512 + bx * 16 + tx;
        #pragma unroll
        for (int oc = 0; oc < 3; ++oc) {
            float a = lhb[oc];
            #pragma unroll
            for (int c = 0; c < 3; ++c)
                #pragma unroll
                for (int t9 = 0; t9 < 9; ++t9) {
                    int dy = t9 / 3, dx = t9 - dy * 3;
                    a = fmaf(lh_t[c * 324 + (ty + dy) * 18 + tx + dx],
                             lhw[(oc * 3 + c) * 9 + t9], a);
                }
            L_out[(size_t)oc * HW_ + pix] = tanhf(a);
        }
    }

    // Epilogue -> fp16 interleaved. C-layout: lane(px,g) reg r -> channel
    // m*16+g*4+r. Pair lanes g^1 via shfl_xor(16) to form 8-channel chunks.
    const int gx0 = bx * 16 + px;
    const int gpair = g >> 1;
    #pragma unroll
    for (int f = 0; f < 4; ++f) {
        const int gy = by * 16 + 4 * wv + f;
        _Float16* orow = out + ((size_t)gy * 512 + gx0) * 64;
        uint2 mine[4], theirs[4];
        #pragma unroll
        for (int m = 0; m < 4; ++m) {
            union { _Float16 h[4]; uint2 u; } pk;
            #pragma unroll
            for (int r = 0; r < 4; ++r) {
                int o = m * 16 + g * 4 + r;
                float v = acc[m][f][r] + bs[m][r];
                if (ACT) v = fmaxf(v, 0.f);
                pk.h[r] = (o < O) ? (_Float16)v : (_Float16)0.f;
            }
            mine[m] = pk.u;
            theirs[m].x = __shfl_xor((int)pk.u.x, 16);
            theirs[m].y = __shfl_xor((int)pk.u.y, 16);
        }
        #pragma unroll
        for (int mm = 0; mm < 2; ++mm) {
            int m = (g & 1) * 2 + mm;
            union { uint2 u[2]; half8 v; } st;
            if ((g & 1) == 0) { st.u[0] = mine[m];   st.u[1] = theirs[m]; }
            else              { st.u[0] = theirs[m]; st.u[1] = mine[m];   }
            *(half8*)(orow + m * 16 + gpair * 8) = st.v;
        }
    }
}

// ---------------- MFMA stride-2 conv + relu + fused 2x2 maxpool -----------
template<int FP32OUT>
__global__ __launch_bounds__(256, 3)
void conv_s2_pool_k(const _Float16* __restrict__ in, int Hin,
                    const _Float16* __restrict__ wt,
                    const float* __restrict__ bias, void* __restrict__ outv,
                    const _Float16* __restrict__ zg)
{
    const int Hp = Hin >> 2;
    __shared__ _Float16 __attribute__((aligned(16))) in_t[2560 * 8]; // 40960 B
    const int tid = threadIdx.x;
    const int l = tid & 63, wv = tid >> 6;
    const int n = l & 15, g = l >> 4;
    const int bx = blockIdx.x, by = blockIdx.y;
    const int iy0 = by * 16 - 1, ix0 = bx * 16 - 1;

    #pragma unroll
    for (int k = 0; k < 10; ++k) {
        int i = tid + (k << 8);
        int p = i >> 3, jl = i & 7;
        int iy = p / 17, ix = p - iy * 17;
        int gy = iy0 + iy, gx = ix0 + ix;
        int j = jl ^ (p & 7);
        const _Float16* src =
            (p < 289 && (unsigned)gy < (unsigned)Hin && (unsigned)gx < (unsigned)Hin)
                ? in + ((size_t)gy * Hin + gx) * 64 + j * 8 : zg;
        __builtin_amdgcn_global_load_lds(
            (const __attribute__((address_space(1))) void*)src,
            (__attribute__((address_space(3))) void*)(in_t + (size_t)(tid - l + (k << 8)) * 8),
            16, 0, 0);
    }
    __syncthreads();

    float bs[4];
    #pragma unroll
    for (int r = 0; r < 4; ++r) bs[r] = bias[wv * 16 + g * 4 + r];

    f32x4 acc[4];
    #pragma unroll
    for (int f = 0; f < 4; ++f) acc[f] = (f32x4){0.f, 0.f, 0.f, 0.f};

    const int py_lo = n >> 3, pxc = n & 7;
    #pragma unroll
    for (int s = 0; s < 9; ++s) {
        const int dy = s / 3, dx = s - dy * 3;
        half8 a[2];
        #pragma unroll
        for (int kk = 0; kk < 2; ++kk)
            a[kk] = *(const half8*)(wt + (size_t)(s * 8 + kk * 4 + wv) * 512 + l * 8);
        #pragma unroll
        for (int f = 0; f < 4; ++f) {
            int py = 2 * f + py_lo;
            int ipix = (2 * py + dy) * 17 + 2 * pxc + dx;
            int rb = ipix * 64, sw = (ipix & 7) << 3;
            #pragma unroll
            for (int kk = 0; kk < 2; ++kk) {
                half8 b = *(const half8*)&in_t[rb + ((kk * 32 + g * 8) ^ sw)];
                acc[f] = __builtin_amdgcn_mfma_f32_16x16x32_f16(a[kk], b, acc[f], 0, 0, 0);
            }
        }
    }

    #pragma unroll
    for (int f = 0; f < 4; ++f)
        #pragma unroll
        for (int r = 0; r < 4; ++r) {
            float v = fmaxf(acc[f][r] + bs[r], 0.f);
            v = fmaxf(v, __shfl_xor(v, 1));
            v = fmaxf(v, __shfl_xor(v, 8));
            if ((l & 9) == 0) {
                int o = wv * 16 + g * 4 + r;
                size_t pp = ((size_t)(by * 4 + f) * Hp + bx * 4 + (n >> 1)) * 64 + o;
                if (FP32OUT) ((float*)outv)[pp] = v;
                else         ((_Float16*)outv)[pp] = (_Float16)v;
            }
        }
}

// ---------------- tail ----------------------------------------------------
__global__ void meanlin_k(const float* __restrict__ h,   // [64pix][64ch] f32
                          const float* __restrict__ lw,
                          const float* __restrict__ lb,
                          float* __restrict__ wm)
{
    __shared__ float g[64];
    int t = threadIdx.x;
    if (t < 64) {
        float s = 0.f;
        for (int p = 0; p < 64; ++p) s += h[p * 64 + t];
        g[t] = s * (1.f / 64.f);
    }
    __syncthreads();
    if (t < 30) {
        float s = lb[t];
        for (int c = 0; c < 64; ++c) s = fmaf(g[c], lw[t * 64 + c], s);
        wm[t] = s;
    }
}

__global__ __launch_bounds__(256)
void final_k(const float* __restrict__ I3, const float* __restrict__ wm,
             float* __restrict__ out)
{
    __shared__ float W[30];
    if (threadIdx.x < 30) W[threadIdx.x] = wm[threadIdx.x];
    __syncthreads();
    const int HW = 512 * 512;
    for (int i = blockIdx.x * blockDim.x + threadIdx.x; i < HW;
         i += gridDim.x * blockDim.x) {
        float r = I3[i], g = I3[HW + i], b = I3[2 * HW + i];
        float f[10] = { r * r, r * g, r * b, r, g * g, g * b, g, b * b, b, 1.f };
        #pragma unroll
        for (int o = 0; o < 3; ++o) {
            float s = 0.f;
            #pragma unroll
            for (int k = 0; k < 10; ++k) s = fmaf(W[o * 10 + k], f[k], s);
            out[(size_t)o * HW + i] = s;
        }
    }
}

extern "C" void kernel_launch(void* const* d_in, const int* in_sizes, int n_in,
                              void* d_out, int out_size, void* d_ws, size_t ws_size,
                              hipStream_t stream)
{
    const float* x      = (const float*)d_in[0];
    const float* low0_w = (const float*)d_in[1];
    const float* low0_b = (const float*)d_in[2];
    const float* rh_w   = (const float*)d_in[3];
    const float* rh_b   = (const float*)d_in[4];
    const float* lh_w   = (const float*)d_in[5];
    const float* lh_b   = (const float*)d_in[6];
    const float* hl0_w  = (const float*)d_in[7];
    const float* hl0_b  = (const float*)d_in[8];
    const float* hl_w   = (const float*)d_in[9];
    const float* hl_b   = (const float*)d_in[10];
    const float* lin_w  = (const float*)d_in[11];
    const float* lin_b  = (const float*)d_in[12];
    float* out = (float*)d_out;

    const size_t HW = 512 * 512;
    _Float16* M0 = (_Float16*)d_ws;                       // [HW][64]
    _Float16* M1 = M0 + (size_t)64 * HW;
    _Float16* P0 = M1 + (size_t)64 * HW;                  // [16384][64]
    _Float16* P1 = P0 + (size_t)16384 * 64;               // [1024][64]
    _Float16* WT = P1 + (size_t)1024 * 64;                // 8*36864
    _Float16* ZG = WT + (size_t)8 * 36864;                // 32-half zero guard
    float*    P2 = (float*)(ZG + 32);                     // [64][64] f32
    float*    L0 = P2 + 64 * 64;                          // 3 fp32 planes
    float*    L1 = L0 + (size_t)3 * HW;
    float*    WM = L1 + (size_t)3 * HW;                   // 30 (pad 32)

    dim3 blk(256);
    dim3 g512(32, 32, 1);

    wtrans_k<<<dim3(144), blk, 0, stream>>>(rh_w, hl0_w, hl_w, WT, ZG);

    // I = conv(x): fp16 interleaved M0 + exact fp32 ch61..63 -> L0
    low0_k<<<dim3(32, 32, 4), blk, 0, stream>>>(x, low0_w, low0_b, M0, L0);

    _Float16* cur = M0; _Float16* nxt = M1;
    float* Lc = L0; float* Ln = L1;
    for (int i = 0; i < 4; ++i) {
        conv_mfma_k<61, 1, 1><<<g512, blk, 0, stream>>>(
            cur, WT + (size_t)i * 36864, rh_b + i * 61, nxt,
            Lc, lh_w + (size_t)i * 81, lh_b + i * 3, Ln, ZG);
        _Float16* t = cur; cur = nxt; nxt = t;
        float* tl = Lc; Lc = Ln; Ln = tl;
    }

    // h = conv(I[:, :61]) -> 64ch fp16 interleaved
    conv_mfma_k<64, 0, 0><<<g512, blk, 0, stream>>>(
        cur, WT + (size_t)4 * 36864, hl0_b, nxt,
        nullptr, nullptr, nullptr, nullptr, ZG);

    conv_s2_pool_k<0><<<dim3(32, 32), blk, 0, stream>>>(
        nxt, 512, WT + (size_t)5 * 36864, hl_b, (void*)P0, ZG);
    conv_s2_pool_k<0><<<dim3(8, 8), blk, 0, stream>>>(
        P0, 128, WT + (size_t)6 * 36864, hl_b + 64, (void*)P1, ZG);
    conv_s2_pool_k<1><<<dim3(2, 2), blk, 0, stream>>>(
        P1, 32, WT + (size_t)7 * 36864, hl_b + 128, (void*)P2, ZG);

    meanlin_k<<<dim3(1), dim3(64), 0, stream>>>(P2, lin_w, lin_b, WM);

    final_k<<<dim3(2048), blk, 0, stream>>>(Lc, WM, out);
}

// Round 6
// 259.740 us; speedup vs baseline: 12.6399x; 1.0989x over previous
//
#include <hip/hip_runtime.h>
#include <cstdint>

typedef _Float16 half8 __attribute__((ext_vector_type(8)));
typedef float f32x4 __attribute__((ext_vector_type(4)));

#define HW_ (512*512)

// ---------------- weight transform: fp32 -> frag-linear fp16 --------------
// 8 layers: 0-3 rh (O=61,CIN=61), 4 hl0 (O=64,CIN=61), 5-7 hl (O=64,CIN=64).
// Per layer 36864 halfs: chunk ci = s*8 + kk*4 + m, 512 halfs per chunk.
// Element (lane,j): A[o = m*16 + (lane&15)][c = kk*32 + (lane>>4)*8 + j].
// Block 0 also zeroes the 32-half guard region ZG (OOB staging target).
__global__ __launch_bounds__(256) void wtrans_k(
    const float* __restrict__ rh_w, const float* __restrict__ hl0_w,
    const float* __restrict__ hl_w, _Float16* __restrict__ wt,
    _Float16* __restrict__ zg)
{
    if (blockIdx.x == 0 && threadIdx.x < 32) zg[threadIdx.x] = (_Float16)0.f;
    int t = blockIdx.x * 256 + threadIdx.x;
    if (t >= 8 * 4608) return;
    int layer = t / 4608;
    int r = t - layer * 4608;
    int lane = r & 63, ci = r >> 6;
    int m = ci & 3, kk = (ci >> 2) & 1, s = ci >> 3;
    int o = m * 16 + (lane & 15);
    int cb = kk * 32 + ((lane >> 4) & 3) * 8;
    const float* w; int O, CIN;
    if (layer < 4)      { w = rh_w + (size_t)layer * 61 * 61 * 9; O = 61; CIN = 61; }
    else if (layer == 4){ w = hl0_w;                              O = 64; CIN = 61; }
    else                { w = hl_w + (size_t)(layer - 5) * 64 * 64 * 9; O = 64; CIN = 64; }
    half8 v;
    #pragma unroll
    for (int j = 0; j < 8; ++j) {
        int c = cb + j;
        float f = (o < O && c < CIN) ? w[((size_t)o * CIN + c) * 9 + s] : 0.f;
        v[j] = (_Float16)f;
    }
    *(half8*)(wt + (size_t)layer * 36864 + (size_t)r * 8) = v;
}

// ---------------- low0: 3->64 fp32 conv, writes interleaved fp16 + L ------
__global__ __launch_bounds__(256)
void low0_k(const float* __restrict__ x, const float* __restrict__ w,
            const float* __restrict__ bias, _Float16* __restrict__ M,
            float* __restrict__ L)
{
    __shared__ float tile[3 * 324];
    const int tx = threadIdx.x & 15, ty = threadIdx.x >> 4;
    const int bx = blockIdx.x, by = blockIdx.y, z = blockIdx.z;
    const int ox = bx * 16 + tx, oy = by * 16 + ty;
    const int ix0 = bx * 16 - 1, iy0 = by * 16 - 1;

    for (int i = threadIdx.x; i < 3 * 324; i += 256) {
        int c = i / 324, p = i - c * 324;
        int iy = p / 18, ix = p - iy * 18;
        int gy = iy0 + iy, gx = ix0 + ix;
        float v = 0.f;
        if ((unsigned)gy < 512u && (unsigned)gx < 512u)
            v = x[(size_t)c * HW_ + (size_t)gy * 512 + gx];
        tile[i] = v;
    }
    __syncthreads();

    float p9[3][9];
    #pragma unroll
    for (int c = 0; c < 3; ++c)
        #pragma unroll
        for (int dy = 0; dy < 3; ++dy)
            #pragma unroll
            for (int dx = 0; dx < 3; ++dx)
                p9[c][dy * 3 + dx] = tile[c * 324 + (ty + dy) * 18 + tx + dx];

    float acc[16];
    #pragma unroll
    for (int o = 0; o < 16; ++o) {
        int oc = z * 16 + o;
        float a = bias[oc];
        const float* wo = w + (size_t)oc * 27;
        #pragma unroll
        for (int c = 0; c < 3; ++c)
            #pragma unroll
            for (int k = 0; k < 9; ++k)
                a = fmaf(p9[c][k], wo[c * 9 + k], a);
        acc[o] = a;
    }

    const size_t pix = (size_t)oy * 512 + ox;
    half8 h0, h1;
    #pragma unroll
    for (int o = 0; o < 8; ++o) { h0[o] = (_Float16)acc[o]; h1[o] = (_Float16)acc[8 + o]; }
    _Float16* orow = M + pix * 64 + z * 16;
    *(half8*)(orow)     = h0;
    *(half8*)(orow + 8) = h1;
    if (z == 3) {
        #pragma unroll
        for (int o = 13; o < 16; ++o)
            L[(size_t)(o - 13) * HW_ + pix] = acc[o];
    }
}

// ---------------- MFMA implicit-GEMM conv, stride 1, 512x512 --------------
// IO: fp16 channel-interleaved [pixel][64]. LDS [p][c ^ ((p&7)<<3)].
// Staging via global_load_lds width=16 (LDS dest linear; swizzle folded into
// per-lane SOURCE index; OOB lanes read zero guard zg). Epilogue transposes
// through in_t (reused) so global stores are dense 1 KB/wave.
// DOLH: fused 3->3 tanh conv (lh chain, exact fp32 path).
template<int O, int ACT, int DOLH>
__global__ __launch_bounds__(256, 3)
void conv_mfma_k(const _Float16* __restrict__ in, const _Float16* __restrict__ wt,
                 const float* __restrict__ bias, _Float16* __restrict__ out,
                 const float* __restrict__ L_in, const float* __restrict__ lhw,
                 const float* __restrict__ lhb, float* __restrict__ L_out,
                 const _Float16* __restrict__ zg)
{
    __shared__ _Float16 __attribute__((aligned(16))) in_t[2816 * 8]; // 45056 B
    __shared__ float lh_t[3 * 324];
    const int tid = threadIdx.x;
    const int l = tid & 63, wv = tid >> 6;
    const int px = l & 15, g = l >> 4;
    const int bx = blockIdx.x, by = blockIdx.y;
    const int iy0 = by * 16 - 1, ix0 = bx * 16 - 1;

    #pragma unroll
    for (int k = 0; k < 11; ++k) {
        int i = tid + (k << 8);
        int p = i >> 3, jl = i & 7;
        int iy = p / 18, ix = p - iy * 18;
        int gy = iy0 + iy, gx = ix0 + ix;
        int j = jl ^ (p & 7);
        const _Float16* src =
            (p < 324 && (unsigned)gy < 512u && (unsigned)gx < 512u)
                ? in + ((size_t)gy * 512 + gx) * 64 + j * 8 : zg;
        __builtin_amdgcn_global_load_lds(
            (const __attribute__((address_space(1))) void*)src,
            (__attribute__((address_space(3))) void*)(in_t + (size_t)(tid - l + (k << 8)) * 8),
            16, 0, 0);
    }
    if (DOLH) {
        for (int i = tid; i < 3 * 324; i += 256) {
            int c = i / 324, p = i - c * 324;
            int iy = p / 18, ix = p - iy * 18;
            int gy = iy0 + iy, gx = ix0 + ix;
            float v = 0.f;
            if ((unsigned)gy < 512u && (unsigned)gx < 512u)
                v = L_in[(size_t)c * HW_ + (size_t)gy * 512 + gx];
            lh_t[i] = v;
        }
    }
    __syncthreads();

    float bs[4][4];
    #pragma unroll
    for (int m = 0; m < 4; ++m)
        #pragma unroll
        for (int r = 0; r < 4; ++r) {
            int o = m * 16 + g * 4 + r;
            bs[m][r] = (o < O) ? bias[o] : 0.f;
        }

    f32x4 acc[4][4];
    #pragma unroll
    for (int m = 0; m < 4; ++m)
        #pragma unroll
        for (int f = 0; f < 4; ++f) acc[m][f] = (f32x4){0.f, 0.f, 0.f, 0.f};

    const _Float16* wb = wt + (size_t)l * 8;
    half8 aA[8], aB[8];
    #pragma unroll
    for (int q = 0; q < 8; ++q) aA[q] = *(const half8*)(wb + q * 512);

    #pragma unroll
    for (int s = 0; s < 9; ++s) {
        asm volatile("" ::: "memory");
        const half8* ac = (s & 1) ? aB : aA;
        half8*       an = (s & 1) ? aA : aB;
        if (s < 8) {
            #pragma unroll
            for (int q = 0; q < 8; ++q)
                an[q] = *(const half8*)(wb + ((s + 1) * 8 + q) * 512);
        }
        const int dy = s / 3, dx = s - dy * 3;
        #pragma unroll
        for (int f = 0; f < 4; ++f) {
            int ipix = (4 * wv + f + dy) * 18 + px + dx;
            int rb = ipix * 64, sw = (ipix & 7) << 3;
            #pragma unroll
            for (int kk = 0; kk < 2; ++kk) {
                half8 b = *(const half8*)&in_t[rb + ((kk * 32 + g * 8) ^ sw)];
                #pragma unroll
                for (int m = 0; m < 4; ++m)
                    acc[m][f] = __builtin_amdgcn_mfma_f32_16x16x32_f16(
                        ac[kk * 4 + m], b, acc[m][f], 0, 0, 0);
            }
        }
    }

    // fused lh: 3->3 fp32 conv + tanh on exact path (independent chain)
    if (DOLH) {
        const int tx = tid & 15, ty = tid >> 4;
        const size_t pix = (size_t)(by * 16 + ty) * 512 + bx * 16 + tx;
        #pragma unroll
        for (int oc = 0; oc < 3; ++oc) {
            float a = lhb[oc];
            #pragma unroll
            for (int c = 0; c < 3; ++c)
                #pragma unroll
                for (int t9 = 0; t9 < 9; ++t9) {
                    int dy = t9 / 3, dx = t9 - dy * 3;
                    a = fmaf(lh_t[c * 324 + (ty + dy) * 18 + tx + dx],
                             lhw[(oc * 3 + c) * 9 + t9], a);
                }
            L_out[(size_t)oc * HW_ + pix] = tanhf(a);
        }
    }

    // ---- epilogue: transpose via LDS (reuse in_t) -> dense 1KB stores ----
    __syncthreads();                      // all waves done reading in_t
    #pragma unroll
    for (int f = 0; f < 4; ++f) {
        const int p = (4 * wv + f) * 16 + px;
        const int sw = p & 7;
        #pragma unroll
        for (int m = 0; m < 4; ++m) {
            union { _Float16 h[4]; uint2 u; } pk;
            #pragma unroll
            for (int r = 0; r < 4; ++r) {
                int o = m * 16 + g * 4 + r;
                float v = acc[m][f][r] + bs[m][r];
                if (ACT) v = fmaxf(v, 0.f);
                pk.h[r] = (o < O) ? (_Float16)v : (_Float16)0.f;
            }
            int chunk = (m * 2 + (g >> 1)) ^ sw;
            *(uint2*)&in_t[p * 64 + chunk * 8 + (g & 1) * 4] = pk.u;
        }
    }
    __syncthreads();
    // pixel-linear read-back; wave stores are contiguous 1 KB.
    #pragma unroll
    for (int k = 0; k < 8; ++k) {
        int q = (k << 8) + tid;           // chunk id 0..2047
        int p = q >> 3, jc = q & 7;
        half8 v = *(const half8*)&in_t[p * 64 + ((jc ^ (p & 7)) * 8)];
        int row = p >> 4, col = p & 15;
        _Float16* dst = out + (((size_t)(by * 16 + row) * 512) + bx * 16 + col) * 64 + jc * 8;
        *(half8*)dst = v;
    }
}

// ---------------- MFMA stride-2 conv + relu + fused 2x2 maxpool -----------
template<int FP32OUT>
__global__ __launch_bounds__(256, 3)
void conv_s2_pool_k(const _Float16* __restrict__ in, int Hin,
                    const _Float16* __restrict__ wt,
                    const float* __restrict__ bias, void* __restrict__ outv,
                    const _Float16* __restrict__ zg)
{
    const int Hp = Hin >> 2;
    __shared__ _Float16 __attribute__((aligned(16))) in_t[2560 * 8]; // 40960 B
    const int tid = threadIdx.x;
    const int l = tid & 63, wv = tid >> 6;
    const int n = l & 15, g = l >> 4;
    const int bx = blockIdx.x, by = blockIdx.y;
    const int iy0 = by * 16 - 1, ix0 = bx * 16 - 1;

    #pragma unroll
    for (int k = 0; k < 10; ++k) {
        int i = tid + (k << 8);
        int p = i >> 3, jl = i & 7;
        int iy = p / 17, ix = p - iy * 17;
        int gy = iy0 + iy, gx = ix0 + ix;
        int j = jl ^ (p & 7);
        const _Float16* src =
            (p < 289 && (unsigned)gy < (unsigned)Hin && (unsigned)gx < (unsigned)Hin)
                ? in + ((size_t)gy * Hin + gx) * 64 + j * 8 : zg;
        __builtin_amdgcn_global_load_lds(
            (const __attribute__((address_space(1))) void*)src,
            (__attribute__((address_space(3))) void*)(in_t + (size_t)(tid - l + (k << 8)) * 8),
            16, 0, 0);
    }
    __syncthreads();

    float bs[4];
    #pragma unroll
    for (int r = 0; r < 4; ++r) bs[r] = bias[wv * 16 + g * 4 + r];

    f32x4 acc[4];
    #pragma unroll
    for (int f = 0; f < 4; ++f) acc[f] = (f32x4){0.f, 0.f, 0.f, 0.f};

    const int py_lo = n >> 3, pxc = n & 7;
    #pragma unroll
    for (int s = 0; s < 9; ++s) {
        const int dy = s / 3, dx = s - dy * 3;
        half8 a[2];
        #pragma unroll
        for (int kk = 0; kk < 2; ++kk)
            a[kk] = *(const half8*)(wt + (size_t)(s * 8 + kk * 4 + wv) * 512 + l * 8);
        #pragma unroll
        for (int f = 0; f < 4; ++f) {
            int py = 2 * f + py_lo;
            int ipix = (2 * py + dy) * 17 + 2 * pxc + dx;
            int rb = ipix * 64, sw = (ipix & 7) << 3;
            #pragma unroll
            for (int kk = 0; kk < 2; ++kk) {
                half8 b = *(const half8*)&in_t[rb + ((kk * 32 + g * 8) ^ sw)];
                acc[f] = __builtin_amdgcn_mfma_f32_16x16x32_f16(a[kk], b, acc[f], 0, 0, 0);
            }
        }
    }

    #pragma unroll
    for (int f = 0; f < 4; ++f)
        #pragma unroll
        for (int r = 0; r < 4; ++r) {
            float v = fmaxf(acc[f][r] + bs[r], 0.f);
            v = fmaxf(v, __shfl_xor(v, 1));
            v = fmaxf(v, __shfl_xor(v, 8));
            if ((l & 9) == 0) {
                int o = wv * 16 + g * 4 + r;
                size_t pp = ((size_t)(by * 4 + f) * Hp + bx * 4 + (n >> 1)) * 64 + o;
                if (FP32OUT) ((float*)outv)[pp] = v;
                else         ((_Float16*)outv)[pp] = (_Float16)v;
            }
        }
}

// ---------------- tail ----------------------------------------------------
__global__ void meanlin_k(const float* __restrict__ h,   // [64pix][64ch] f32
                          const float* __restrict__ lw,
                          const float* __restrict__ lb,
                          float* __restrict__ wm)
{
    __shared__ float g[64];
    int t = threadIdx.x;
    if (t < 64) {
        float s = 0.f;
        for (int p = 0; p < 64; ++p) s += h[p * 64 + t];
        g[t] = s * (1.f / 64.f);
    }
    __syncthreads();
    if (t < 30) {
        float s = lb[t];
        for (int c = 0; c < 64; ++c) s = fmaf(g[c], lw[t * 64 + c], s);
        wm[t] = s;
    }
}

__global__ __launch_bounds__(256)
void final_k(const float* __restrict__ I3, const float* __restrict__ wm,
             float* __restrict__ out)
{
    __shared__ float W[30];
    if (threadIdx.x < 30) W[threadIdx.x] = wm[threadIdx.x];
    __syncthreads();
    const int HW = 512 * 512;
    for (int i = blockIdx.x * blockDim.x + threadIdx.x; i < HW;
         i += gridDim.x * blockDim.x) {
        float r = I3[i], g = I3[HW + i], b = I3[2 * HW + i];
        float f[10] = { r * r, r * g, r * b, r, g * g, g * b, g, b * b, b, 1.f };
        #pragma unroll
        for (int o = 0; o < 3; ++o) {
            float s = 0.f;
            #pragma unroll
            for (int k = 0; k < 10; ++k) s = fmaf(W[o * 10 + k], f[k], s);
            out[(size_t)o * HW + i] = s;
        }
    }
}

extern "C" void kernel_launch(void* const* d_in, const int* in_sizes, int n_in,
                              void* d_out, int out_size, void* d_ws, size_t ws_size,
                              hipStream_t stream)
{
    const float* x      = (const float*)d_in[0];
    const float* low0_w = (const float*)d_in[1];
    const float* low0_b = (const float*)d_in[2];
    const float* rh_w   = (const float*)d_in[3];
    const float* rh_b   = (const float*)d_in[4];
    const float* lh_w   = (const float*)d_in[5];
    const float* lh_b   = (const float*)d_in[6];
    const float* hl0_w  = (const float*)d_in[7];
    const float* hl0_b  = (const float*)d_in[8];
    const float* hl_w   = (const float*)d_in[9];
    const float* hl_b   = (const float*)d_in[10];
    const float* lin_w  = (const float*)d_in[11];
    const float* lin_b  = (const float*)d_in[12];
    float* out = (float*)d_out;

    const size_t HW = 512 * 512;
    _Float16* M0 = (_Float16*)d_ws;                       // [HW][64]
    _Float16* M1 = M0 + (size_t)64 * HW;
    _Float16* P0 = M1 + (size_t)64 * HW;                  // [16384][64]
    _Float16* P1 = P0 + (size_t)16384 * 64;               // [1024][64]
    _Float16* WT = P1 + (size_t)1024 * 64;                // 8*36864
    _Float16* ZG = WT + (size_t)8 * 36864;                // 32-half zero guard
    float*    P2 = (float*)(ZG + 32);                     // [64][64] f32
    float*    L0 = P2 + 64 * 64;                          // 3 fp32 planes
    float*    L1 = L0 + (size_t)3 * HW;
    float*    WM = L1 + (size_t)3 * HW;                   // 30 (pad 32)

    dim3 blk(256);
    dim3 g512(32, 32, 1);

    wtrans_k<<<dim3(144), blk, 0, stream>>>(rh_w, hl0_w, hl_w, WT, ZG);

    // I = conv(x): fp16 interleaved M0 + exact fp32 ch61..63 -> L0
    low0_k<<<dim3(32, 32, 4), blk, 0, stream>>>(x, low0_w, low0_b, M0, L0);

    _Float16* cur = M0; _Float16* nxt = M1;
    float* Lc = L0; float* Ln = L1;
    for (int i = 0; i < 4; ++i) {
        conv_mfma_k<61, 1, 1><<<g512, blk, 0, stream>>>(
            cur, WT + (size_t)i * 36864, rh_b + i * 61, nxt,
            Lc, lh_w + (size_t)i * 81, lh_b + i * 3, Ln, ZG);
        _Float16* t = cur; cur = nxt; nxt = t;
        float* tl = Lc; Lc = Ln; Ln = tl;
    }

    // h = conv(I[:, :61]) -> 64ch fp16 interleaved
    conv_mfma_k<64, 0, 0><<<g512, blk, 0, stream>>>(
        cur, WT + (size_t)4 * 36864, hl0_b, nxt,
        nullptr, nullptr, nullptr, nullptr, ZG);

    conv_s2_pool_k<0><<<dim3(32, 32), blk, 0, stream>>>(
        nxt, 512, WT + (size_t)5 * 36864, hl_b, (void*)P0, ZG);
    conv_s2_pool_k<0><<<dim3(8, 8), blk, 0, stream>>>(
        P0, 128, WT + (size_t)6 * 36864, hl_b + 64, (void*)P1, ZG);
    conv_s2_pool_k<1><<<dim3(2, 2), blk, 0, stream>>>(
        P1, 32, WT + (size_t)7 * 36864, hl_b + 128, (void*)P2, ZG);

    meanlin_k<<<dim3(1), dim3(64), 0, stream>>>(P2, lin_w, lin_b, WM);

    final_k<<<dim3(2048), blk, 0, stream>>>(Lc, WM, out);
}

// Round 7
// 228.904 us; speedup vs baseline: 14.3427x; 1.1347x over previous
//
#include <hip/hip_runtime.h>
#include <cstdint>

typedef _Float16 half8 __attribute__((ext_vector_type(8)));
typedef float f32x4 __attribute__((ext_vector_type(4)));

#define HW_ (512*512)

// ---------------- weight transform: fp32 -> frag-linear fp16 --------------
// 8 layers: 0-3 rh (O=61,CIN=61), 4 hl0 (O=64,CIN=61), 5-7 hl (O=64,CIN=64).
// Per layer 36864 halfs: chunk ci = s*8 + kk*4 + m, 512 halfs per chunk.
// Element (lane,j): A[o = m*16 + (lane&15)][c = kk*32 + (lane>>4)*8 + j].
// Tap slice s = 4096 contiguous halfs (chunks s*8..s*8+7).
// Block 0 also zeroes the 32-half guard region ZG (OOB staging target).
__global__ __launch_bounds__(256) void wtrans_k(
    const float* __restrict__ rh_w, const float* __restrict__ hl0_w,
    const float* __restrict__ hl_w, _Float16* __restrict__ wt,
    _Float16* __restrict__ zg)
{
    if (blockIdx.x == 0 && threadIdx.x < 32) zg[threadIdx.x] = (_Float16)0.f;
    int t = blockIdx.x * 256 + threadIdx.x;
    if (t >= 8 * 4608) return;
    int layer = t / 4608;
    int r = t - layer * 4608;
    int lane = r & 63, ci = r >> 6;
    int m = ci & 3, kk = (ci >> 2) & 1, s = ci >> 3;
    int o = m * 16 + (lane & 15);
    int cb = kk * 32 + ((lane >> 4) & 3) * 8;
    const float* w; int O, CIN;
    if (layer < 4)      { w = rh_w + (size_t)layer * 61 * 61 * 9; O = 61; CIN = 61; }
    else if (layer == 4){ w = hl0_w;                              O = 64; CIN = 61; }
    else                { w = hl_w + (size_t)(layer - 5) * 64 * 64 * 9; O = 64; CIN = 64; }
    half8 v;
    #pragma unroll
    for (int j = 0; j < 8; ++j) {
        int c = cb + j;
        float f = (o < O && c < CIN) ? w[((size_t)o * CIN + c) * 9 + s] : 0.f;
        v[j] = (_Float16)f;
    }
    *(half8*)(wt + (size_t)layer * 36864 + (size_t)r * 8) = v;
}

// ---------------- low0: 3->64 fp32 conv, writes interleaved fp16 + L ------
__global__ __launch_bounds__(256)
void low0_k(const float* __restrict__ x, const float* __restrict__ w,
            const float* __restrict__ bias, _Float16* __restrict__ M,
            float* __restrict__ L)
{
    __shared__ float tile[3 * 324];
    const int tx = threadIdx.x & 15, ty = threadIdx.x >> 4;
    const int bx = blockIdx.x, by = blockIdx.y, z = blockIdx.z;
    const int ox = bx * 16 + tx, oy = by * 16 + ty;
    const int ix0 = bx * 16 - 1, iy0 = by * 16 - 1;

    for (int i = threadIdx.x; i < 3 * 324; i += 256) {
        int c = i / 324, p = i - c * 324;
        int iy = p / 18, ix = p - iy * 18;
        int gy = iy0 + iy, gx = ix0 + ix;
        float v = 0.f;
        if ((unsigned)gy < 512u && (unsigned)gx < 512u)
            v = x[(size_t)c * HW_ + (size_t)gy * 512 + gx];
        tile[i] = v;
    }
    __syncthreads();

    float p9[3][9];
    #pragma unroll
    for (int c = 0; c < 3; ++c)
        #pragma unroll
        for (int dy = 0; dy < 3; ++dy)
            #pragma unroll
            for (int dx = 0; dx < 3; ++dx)
                p9[c][dy * 3 + dx] = tile[c * 324 + (ty + dy) * 18 + tx + dx];

    float acc[16];
    #pragma unroll
    for (int o = 0; o < 16; ++o) {
        int oc = z * 16 + o;
        float a = bias[oc];
        const float* wo = w + (size_t)oc * 27;
        #pragma unroll
        for (int c = 0; c < 3; ++c)
            #pragma unroll
            for (int k = 0; k < 9; ++k)
                a = fmaf(p9[c][k], wo[c * 9 + k], a);
        acc[o] = a;
    }

    const size_t pix = (size_t)oy * 512 + ox;
    half8 h0, h1;
    #pragma unroll
    for (int o = 0; o < 8; ++o) { h0[o] = (_Float16)acc[o]; h1[o] = (_Float16)acc[8 + o]; }
    _Float16* orow = M + pix * 64 + z * 16;
    *(half8*)(orow)     = h0;
    *(half8*)(orow + 8) = h1;
    if (z == 3) {
        #pragma unroll
        for (int o = 13; o < 16; ++o)
            L[(size_t)(o - 13) * HW_ + pix] = acc[o];
    }
}

// ---------------- MFMA implicit-GEMM conv, stride 1, 512x512 --------------
// IO: fp16 channel-interleaved [pixel][64]. LDS [p][c ^ ((p&7)<<3)].
// Activations staged via global_load_lds width=16; weights staged PER TAP
// (8 KB slice, double-buffered) into LDS and read as A-frags by all 4 waves
// (cuts L2 weight traffic 4x vs per-wave global prefetch). Per tap:
// issue next-slice loads -> compute from LDS -> barrier (mini 2-phase).
// Epilogue transposes via in_t so global stores are dense 1 KB/wave.
template<int O, int ACT, int DOLH>
__global__ __launch_bounds__(256, 2)
void conv_mfma_k(const _Float16* __restrict__ in, const _Float16* __restrict__ wt,
                 const float* __restrict__ bias, _Float16* __restrict__ out,
                 const float* __restrict__ L_in, const float* __restrict__ lhw,
                 const float* __restrict__ lhb, float* __restrict__ L_out,
                 const _Float16* __restrict__ zg)
{
    __shared__ _Float16 __attribute__((aligned(16))) in_t[2592 * 8];   // 41472 B
    __shared__ _Float16 __attribute__((aligned(16))) wbuf[2][4096];    // 16384 B
    __shared__ float lh_t[DOLH ? 3 * 324 : 4];
    const int tid = threadIdx.x;
    const int l = tid & 63, wv = tid >> 6;
    const int px = l & 15, g = l >> 4;
    const int bx = blockIdx.x, by = blockIdx.y;
    const int iy0 = by * 16 - 1, ix0 = bx * 16 - 1;

    // stage activations (2592 chunks) + tap-0 weights (512 chunks)
    #pragma unroll
    for (int k = 0; k < 11; ++k) {
        int i = tid + (k << 8);
        if (i < 2592) {
            int p = i >> 3, jl = i & 7;
            int iy = p / 18, ix = p - iy * 18;
            int gy = iy0 + iy, gx = ix0 + ix;
            int j = jl ^ (p & 7);
            const _Float16* src = ((unsigned)gy < 512u && (unsigned)gx < 512u)
                ? in + ((size_t)gy * 512 + gx) * 64 + j * 8 : zg;
            __builtin_amdgcn_global_load_lds(
                (const __attribute__((address_space(1))) void*)src,
                (__attribute__((address_space(3))) void*)(in_t + (size_t)(i - l) * 8),
                16, 0, 0);
        }
    }
    #pragma unroll
    for (int it = 0; it < 2; ++it) {
        int ci = (it << 8) + tid;
        __builtin_amdgcn_global_load_lds(
            (const __attribute__((address_space(1))) void*)(wt + ci * 8),
            (__attribute__((address_space(3))) void*)(wbuf[0] + (size_t)(ci - l) * 8),
            16, 0, 0);
    }
    if (DOLH) {
        for (int i = tid; i < 3 * 324; i += 256) {
            int c = i / 324, p = i - c * 324;
            int iy = p / 18, ix = p - iy * 18;
            int gy = iy0 + iy, gx = ix0 + ix;
            float v = 0.f;
            if ((unsigned)gy < 512u && (unsigned)gx < 512u)
                v = L_in[(size_t)c * HW_ + (size_t)gy * 512 + gx];
            lh_t[i] = v;
        }
    }
    __syncthreads();

    float bs[4][4];
    #pragma unroll
    for (int m = 0; m < 4; ++m)
        #pragma unroll
        for (int r = 0; r < 4; ++r) {
            int o = m * 16 + g * 4 + r;
            bs[m][r] = (o < O) ? bias[o] : 0.f;
        }

    f32x4 acc[4][4];
    #pragma unroll
    for (int m = 0; m < 4; ++m)
        #pragma unroll
        for (int f = 0; f < 4; ++f) acc[m][f] = (f32x4){0.f, 0.f, 0.f, 0.f};

    #pragma unroll
    for (int s = 0; s < 9; ++s) {
        // issue next tap's weight slice (lands before next barrier)
        if (s < 8) {
            #pragma unroll
            for (int it = 0; it < 2; ++it) {
                int ci = (it << 8) + tid;
                __builtin_amdgcn_global_load_lds(
                    (const __attribute__((address_space(1))) void*)(wt + ((s + 1) << 12) + ci * 8),
                    (__attribute__((address_space(3))) void*)(wbuf[(s + 1) & 1] + (size_t)(ci - l) * 8),
                    16, 0, 0);
            }
        }
        const _Float16* wb = wbuf[s & 1];
        half8 a[8];
        #pragma unroll
        for (int q = 0; q < 8; ++q)
            a[q] = *(const half8*)(wb + (q << 9) + l * 8);

        const int dy = s / 3, dx = s - dy * 3;
        #pragma unroll
        for (int f = 0; f < 4; ++f) {
            int ipix = (4 * wv + f + dy) * 18 + px + dx;
            int rb = ipix * 64, sw = (ipix & 7) << 3;
            #pragma unroll
            for (int kk = 0; kk < 2; ++kk) {
                half8 b = *(const half8*)&in_t[rb + ((kk * 32 + g * 8) ^ sw)];
                #pragma unroll
                for (int m = 0; m < 4; ++m)
                    acc[m][f] = __builtin_amdgcn_mfma_f32_16x16x32_f16(
                        a[kk * 4 + m], b, acc[m][f], 0, 0, 0);
            }
        }
        __syncthreads();   // wbuf[s&1] free; wbuf[(s+1)&1] landed (vmcnt drain)
    }

    // fused lh: 3->3 fp32 conv + tanh on exact path (independent chain)
    if (DOLH) {
        const int tx = tid & 15, ty = tid >> 4;
        const size_t pix = (size_t)(by * 16 + ty) * 512 + bx * 16 + tx;
        #pragma unroll
        for (int oc = 0; oc < 3; ++oc) {
            float a = lhb[oc];
            #pragma unroll
            for (int c = 0; c < 3; ++c)
                #pragma unroll
                for (int t9 = 0; t9 < 9; ++t9) {
                    int dy = t9 / 3, dx = t9 - dy * 3;
                    a = fmaf(lh_t[c * 324 + (ty + dy) * 18 + tx + dx],
                             lhw[(oc * 3 + c) * 9 + t9], a);
                }
            L_out[(size_t)oc * HW_ + pix] = tanhf(a);
        }
    }

    // ---- epilogue: transpose via LDS (reuse in_t) -> dense 1KB stores ----
    #pragma unroll
    for (int f = 0; f < 4; ++f) {
        const int p = (4 * wv + f) * 16 + px;
        const int sw = p & 7;
        #pragma unroll
        for (int m = 0; m < 4; ++m) {
            union { _Float16 h[4]; uint2 u; } pk;
            #pragma unroll
            for (int r = 0; r < 4; ++r) {
                int o = m * 16 + g * 4 + r;
                float v = acc[m][f][r] + bs[m][r];
                if (ACT) v = fmaxf(v, 0.f);
                pk.h[r] = (o < O) ? (_Float16)v : (_Float16)0.f;
            }
            int chunk = (m * 2 + (g >> 1)) ^ sw;
            *(uint2*)&in_t[p * 64 + chunk * 8 + (g & 1) * 4] = pk.u;
        }
    }
    __syncthreads();
    // pixel-linear read-back; wave stores are contiguous 1 KB.
    #pragma unroll
    for (int k = 0; k < 8; ++k) {
        int q = (k << 8) + tid;           // chunk id 0..2047
        int p = q >> 3, jc = q & 7;
        half8 v = *(const half8*)&in_t[p * 64 + ((jc ^ (p & 7)) * 8)];
        int row = p >> 4, col = p & 15;
        _Float16* dst = out + (((size_t)(by * 16 + row) * 512) + bx * 16 + col) * 64 + jc * 8;
        *(half8*)dst = v;
    }
}

// ---------------- MFMA stride-2 conv + relu + fused 2x2 maxpool -----------
// Same per-tap LDS weight staging as conv_mfma_k.
template<int FP32OUT>
__global__ __launch_bounds__(256, 3)
void conv_s2_pool_k(const _Float16* __restrict__ in, int Hin,
                    const _Float16* __restrict__ wt,
                    const float* __restrict__ bias, void* __restrict__ outv,
                    const _Float16* __restrict__ zg)
{
    const int Hp = Hin >> 2;
    __shared__ _Float16 __attribute__((aligned(16))) in_t[2312 * 8];   // 36992 B
    __shared__ _Float16 __attribute__((aligned(16))) wbuf[2][4096];    // 16384 B
    const int tid = threadIdx.x;
    const int l = tid & 63, wv = tid >> 6;
    const int n = l & 15, g = l >> 4;
    const int bx = blockIdx.x, by = blockIdx.y;
    const int iy0 = by * 16 - 1, ix0 = bx * 16 - 1;

    #pragma unroll
    for (int k = 0; k < 10; ++k) {
        int i = tid + (k << 8);
        if (i < 2312) {
            int p = i >> 3, jl = i & 7;
            int iy = p / 17, ix = p - iy * 17;
            int gy = iy0 + iy, gx = ix0 + ix;
            int j = jl ^ (p & 7);
            const _Float16* src =
                ((unsigned)gy < (unsigned)Hin && (unsigned)gx < (unsigned)Hin)
                    ? in + ((size_t)gy * Hin + gx) * 64 + j * 8 : zg;
            __builtin_amdgcn_global_load_lds(
                (const __attribute__((address_space(1))) void*)src,
                (__attribute__((address_space(3))) void*)(in_t + (size_t)(i - l) * 8),
                16, 0, 0);
        }
    }
    #pragma unroll
    for (int it = 0; it < 2; ++it) {
        int ci = (it << 8) + tid;
        __builtin_amdgcn_global_load_lds(
            (const __attribute__((address_space(1))) void*)(wt + ci * 8),
            (__attribute__((address_space(3))) void*)(wbuf[0] + (size_t)(ci - l) * 8),
            16, 0, 0);
    }
    __syncthreads();

    float bs[4];
    #pragma unroll
    for (int r = 0; r < 4; ++r) bs[r] = bias[wv * 16 + g * 4 + r];

    f32x4 acc[4];
    #pragma unroll
    for (int f = 0; f < 4; ++f) acc[f] = (f32x4){0.f, 0.f, 0.f, 0.f};

    const int py_lo = n >> 3, pxc = n & 7;
    #pragma unroll
    for (int s = 0; s < 9; ++s) {
        if (s < 8) {
            #pragma unroll
            for (int it = 0; it < 2; ++it) {
                int ci = (it << 8) + tid;
                __builtin_amdgcn_global_load_lds(
                    (const __attribute__((address_space(1))) void*)(wt + ((s + 1) << 12) + ci * 8),
                    (__attribute__((address_space(3))) void*)(wbuf[(s + 1) & 1] + (size_t)(ci - l) * 8),
                    16, 0, 0);
            }
        }
        const _Float16* wb = wbuf[s & 1];
        half8 a[2];
        #pragma unroll
        for (int kk = 0; kk < 2; ++kk)
            a[kk] = *(const half8*)(wb + ((kk * 4 + wv) << 9) + l * 8);

        const int dy = s / 3, dx = s - dy * 3;
        #pragma unroll
        for (int f = 0; f < 4; ++f) {
            int py = 2 * f + py_lo;
            int ipix = (2 * py + dy) * 17 + 2 * pxc + dx;
            int rb = ipix * 64, sw = (ipix & 7) << 3;
            #pragma unroll
            for (int kk = 0; kk < 2; ++kk) {
                half8 b = *(const half8*)&in_t[rb + ((kk * 32 + g * 8) ^ sw)];
                acc[f] = __builtin_amdgcn_mfma_f32_16x16x32_f16(a[kk], b, acc[f], 0, 0, 0);
            }
        }
        __syncthreads();
    }

    #pragma unroll
    for (int f = 0; f < 4; ++f)
        #pragma unroll
        for (int r = 0; r < 4; ++r) {
            float v = fmaxf(acc[f][r] + bs[r], 0.f);
            v = fmaxf(v, __shfl_xor(v, 1));
            v = fmaxf(v, __shfl_xor(v, 8));
            if ((l & 9) == 0) {
                int o = wv * 16 + g * 4 + r;
                size_t pp = ((size_t)(by * 4 + f) * Hp + bx * 4 + (n >> 1)) * 64 + o;
                if (FP32OUT) ((float*)outv)[pp] = v;
                else         ((_Float16*)outv)[pp] = (_Float16)v;
            }
        }
}

// ---------------- tail ----------------------------------------------------
__global__ void meanlin_k(const float* __restrict__ h,   // [64pix][64ch] f32
                          const float* __restrict__ lw,
                          const float* __restrict__ lb,
                          float* __restrict__ wm)
{
    __shared__ float g[64];
    int t = threadIdx.x;
    if (t < 64) {
        float s = 0.f;
        for (int p = 0; p < 64; ++p) s += h[p * 64 + t];
        g[t] = s * (1.f / 64.f);
    }
    __syncthreads();
    if (t < 30) {
        float s = lb[t];
        for (int c = 0; c < 64; ++c) s = fmaf(g[c], lw[t * 64 + c], s);
        wm[t] = s;
    }
}

__global__ __launch_bounds__(256)
void final_k(const float* __restrict__ I3, const float* __restrict__ wm,
             float* __restrict__ out)
{
    __shared__ float W[30];
    if (threadIdx.x < 30) W[threadIdx.x] = wm[threadIdx.x];
    __syncthreads();
    const int HW = 512 * 512;
    for (int i = blockIdx.x * blockDim.x + threadIdx.x; i < HW;
         i += gridDim.x * blockDim.x) {
        float r = I3[i], g = I3[HW + i], b = I3[2 * HW + i];
        float f[10] = { r * r, r * g, r * b, r, g * g, g * b, g, b * b, b, 1.f };
        #pragma unroll
        for (int o = 0; o < 3; ++o) {
            float s = 0.f;
            #pragma unroll
            for (int k = 0; k < 10; ++k) s = fmaf(W[o * 10 + k], f[k], s);
            out[(size_t)o * HW + i] = s;
        }
    }
}

extern "C" void kernel_launch(void* const* d_in, const int* in_sizes, int n_in,
                              void* d_out, int out_size, void* d_ws, size_t ws_size,
                              hipStream_t stream)
{
    const float* x      = (const float*)d_in[0];
    const float* low0_w = (const float*)d_in[1];
    const float* low0_b = (const float*)d_in[2];
    const float* rh_w   = (const float*)d_in[3];
    const float* rh_b   = (const float*)d_in[4];
    const float* lh_w   = (const float*)d_in[5];
    const float* lh_b   = (const float*)d_in[6];
    const float* hl0_w  = (const float*)d_in[7];
    const float* hl0_b  = (const float*)d_in[8];
    const float* hl_w   = (const float*)d_in[9];
    const float* hl_b   = (const float*)d_in[10];
    const float* lin_w  = (const float*)d_in[11];
    const float* lin_b  = (const float*)d_in[12];
    float* out = (float*)d_out;

    const size_t HW = 512 * 512;
    _Float16* M0 = (_Float16*)d_ws;                       // [HW][64]
    _Float16* M1 = M0 + (size_t)64 * HW;
    _Float16* P0 = M1 + (size_t)64 * HW;                  // [16384][64]
    _Float16* P1 = P0 + (size_t)16384 * 64;               // [1024][64]
    _Float16* WT = P1 + (size_t)1024 * 64;                // 8*36864
    _Float16* ZG = WT + (size_t)8 * 36864;                // 32-half zero guard
    float*    P2 = (float*)(ZG + 32);                     // [64][64] f32
    float*    L0 = P2 + 64 * 64;                          // 3 fp32 planes
    float*    L1 = L0 + (size_t)3 * HW;
    float*    WM = L1 + (size_t)3 * HW;                   // 30 (pad 32)

    dim3 blk(256);
    dim3 g512(32, 32, 1);

    wtrans_k<<<dim3(144), blk, 0, stream>>>(rh_w, hl0_w, hl_w, WT, ZG);

    // I = conv(x): fp16 interleaved M0 + exact fp32 ch61..63 -> L0
    low0_k<<<dim3(32, 32, 4), blk, 0, stream>>>(x, low0_w, low0_b, M0, L0);

    _Float16* cur = M0; _Float16* nxt = M1;
    float* Lc = L0; float* Ln = L1;
    for (int i = 0; i < 4; ++i) {
        conv_mfma_k<61, 1, 1><<<g512, blk, 0, stream>>>(
            cur, WT + (size_t)i * 36864, rh_b + i * 61, nxt,
            Lc, lh_w + (size_t)i * 81, lh_b + i * 3, Ln, ZG);
        _Float16* t = cur; cur = nxt; nxt = t;
        float* tl = Lc; Lc = Ln; Ln = tl;
    }

    // h = conv(I[:, :61]) -> 64ch fp16 interleaved
    conv_mfma_k<64, 0, 0><<<g512, blk, 0, stream>>>(
        cur, WT + (size_t)4 * 36864, hl0_b, nxt,
        nullptr, nullptr, nullptr, nullptr, ZG);

    conv_s2_pool_k<0><<<dim3(32, 32), blk, 0, stream>>>(
        nxt, 512, WT + (size_t)5 * 36864, hl_b, (void*)P0, ZG);
    conv_s2_pool_k<0><<<dim3(8, 8), blk, 0, stream>>>(
        P0, 128, WT + (size_t)6 * 36864, hl_b + 64, (void*)P1, ZG);
    conv_s2_pool_k<1><<<dim3(2, 2), blk, 0, stream>>>(
        P1, 32, WT + (size_t)7 * 36864, hl_b + 128, (void*)P2, ZG);

    meanlin_k<<<dim3(1), dim3(64), 0, stream>>>(P2, lin_w, lin_b, WM);

    final_k<<<dim3(2048), blk, 0, stream>>>(Lc, WM, out);
}